// Round 1
// baseline (6218.938 us; speedup 1.0000x reference)
//
#include <hip/hip_runtime.h>
#include <math.h>

// Problem constants (B,T,E)=(4,2048,512), H=8, D=64, HID=H*E=4096.
#define Bsz 4
#define Tt 2048
#define Ee 512
#define Hh 8
#define Dd 64
#define HIDs 4096
#define Mrows (Bsz * Tt)   // 8192 token rows

// ---------------------------------------------------------------------------
// LayerNorm: one 256-thread block per row of 512. Safe in-place (row values
// are held in registers before any write).
__global__ __launch_bounds__(256) void ln_kernel(const float* __restrict__ x,
        const float* __restrict__ g, const float* __restrict__ b,
        float* __restrict__ out) {
    int row = blockIdx.x;
    int tid = threadIdx.x;
    const float* xr = x + (size_t)row * Ee;
    float v0 = xr[tid];
    float v1 = xr[tid + 256];
    float s = v0 + v1;
    float sq = v0 * v0 + v1 * v1;
#pragma unroll
    for (int off = 32; off > 0; off >>= 1) {
        s  += __shfl_xor(s, off, 64);
        sq += __shfl_xor(sq, off, 64);
    }
    __shared__ float ls[4], lq[4];
    int wid = tid >> 6, lane = tid & 63;
    if (lane == 0) { ls[wid] = s; lq[wid] = sq; }
    __syncthreads();
    s  = ls[0] + ls[1] + ls[2] + ls[3];
    sq = lq[0] + lq[1] + lq[2] + lq[3];
    float mean = s * (1.0f / Ee);
    float var  = sq * (1.0f / Ee) - mean * mean;   // biased var, like jnp.var
    float rstd = rsqrtf(var + 1e-5f);
    float* orow = out + (size_t)row * Ee;
    orow[tid]       = (v0 - mean) * rstd * g[tid]       + b[tid];
    orow[tid + 256] = (v1 - mean) * rstd * g[tid + 256] + b[tid + 256];
}

// ---------------------------------------------------------------------------
// Repack Wq/Wk/Wv [H,E,D] into one plain row-major [E, 3*H*D] B-matrix so the
// QKV projection is a single GEMM producing qkv rows of layout
// [q(h,d) | k(h,d) | v(h,d)] (1536 floats per token).
__global__ __launch_bounds__(256) void repack_qkv(const float* __restrict__ Wq,
        const float* __restrict__ Wk, const float* __restrict__ Wv,
        float* __restrict__ bq) {
    int idx = blockIdx.x * 256 + threadIdx.x;   // < 512*1536
    int e  = idx / 1536;
    int c  = idx % 1536;
    int p  = c >> 9;        // 0=q,1=k,2=v
    int pp = c & 511;
    int h  = pp >> 6;
    int d  = pp & 63;
    const float* W = (p == 0) ? Wq : ((p == 1) ? Wk : Wv);
    bq[idx] = W[(h * Ee + e) * Dd + d];
}

// ---------------------------------------------------------------------------
// fp32 tiled GEMM, 64x64 tile, BK=16, 4x4 per thread. Epilogue modes:
//   0: C = acc
//   1: C = resid + acc + bias[c]        (Wo projection + residual)
//   2: C = relu(acc + bias[c])          (FFN layer 1 chunk)
//   3: C += acc                         (FFN layer 2 chunk accumulate)
__global__ __launch_bounds__(256) void gemm_kernel(
        const float* __restrict__ A, int lda,
        const float* __restrict__ Bm, int ldb,
        float* __restrict__ C, int ldc, int K,
        const float* __restrict__ bias,
        const float* __restrict__ resid, int mode) {
    __shared__ float As[16][64];   // As[k][m]
    __shared__ float Bs[16][64];   // Bs[k][n]
    int tid  = threadIdx.x;
    int row0 = blockIdx.y * 64;
    int col0 = blockIdx.x * 64;
    int tx = tid & 15;             // 4-col group
    int ty = tid >> 4;             // 4-row group
    int a_m = tid >> 2;            // 0..63
    int a_k = (tid & 3) << 2;      // 0,4,8,12
    int b_k = tid >> 4;            // 0..15
    int b_n = (tid & 15) << 2;     // 0..60
    float acc[4][4] = {};
    for (int k0 = 0; k0 < K; k0 += 16) {
        float4 av = *(const float4*)(A + (size_t)(row0 + a_m) * lda + k0 + a_k);
        As[a_k + 0][a_m] = av.x;
        As[a_k + 1][a_m] = av.y;
        As[a_k + 2][a_m] = av.z;
        As[a_k + 3][a_m] = av.w;
        *(float4*)(&Bs[b_k][b_n]) =
            *(const float4*)(Bm + (size_t)(k0 + b_k) * ldb + col0 + b_n);
        __syncthreads();
#pragma unroll
        for (int kk = 0; kk < 16; ++kk) {
            float4 a4 = *(const float4*)(&As[kk][ty << 2]);
            float4 b4 = *(const float4*)(&Bs[kk][tx << 2]);
            float a_[4] = {a4.x, a4.y, a4.z, a4.w};
            float b_[4] = {b4.x, b4.y, b4.z, b4.w};
#pragma unroll
            for (int i = 0; i < 4; ++i)
#pragma unroll
                for (int j = 0; j < 4; ++j)
                    acc[i][j] = fmaf(a_[i], b_[j], acc[i][j]);
        }
        __syncthreads();
    }
#pragma unroll
    for (int i = 0; i < 4; ++i) {
        int r = row0 + (ty << 2) + i;
#pragma unroll
        for (int j = 0; j < 4; ++j) {
            int c = col0 + (tx << 2) + j;
            float v = acc[i][j];
            size_t ci = (size_t)r * ldc + c;
            if (mode == 0) {
                C[ci] = v;
            } else if (mode == 1) {
                C[ci] = resid[ci] + v + bias[c];
            } else if (mode == 2) {
                float vv = v + bias[c];
                C[ci] = vv > 0.0f ? vv : 0.0f;
            } else {
                C[ci] += v;
            }
        }
    }
}

// ---------------------------------------------------------------------------
// Causal attention, online softmax. One wave per (b,h,t); lane = d (D==64).
// Reads q/k/v from the packed qkv buffer (row stride 1536) and writes the
// attention output IN PLACE over the q slot -> natural [B,T,H*D] layout for
// the Wo GEMM (each q row-segment is touched by exactly one wave).
__global__ __launch_bounds__(256) void attn_kernel(float* __restrict__ qkv) {
    int w    = (blockIdx.x * 256 + threadIdx.x) >> 6;
    int lane = threadIdx.x & 63;
    int b    = w >> 14;          // / (H*T) = 16384
    int rem  = w & 16383;
    int h    = rem >> 11;        // / T
    int t    = rem & 2047;
    const float scale = 0.022097086912079608f;   // T**-0.5, per reference
    size_t rowq  = ((size_t)(b * Tt + t)) * 1536 + h * 64 + lane;
    size_t basek = (size_t)(b * Tt) * 1536 + 512 + h * 64 + lane;
    float ql  = qkv[rowq];
    float m   = -1.0e30f, l = 0.0f, acc = 0.0f;
    for (int s = 0; s <= t; ++s) {
        float kl = qkv[basek + (size_t)s * 1536];
        float prod = ql * kl;
#pragma unroll
        for (int off = 32; off > 0; off >>= 1)
            prod += __shfl_xor(prod, off, 64);
        float sc   = prod * scale;
        float mn   = fmaxf(m, sc);
        float corr = __expf(m - mn);
        float p    = __expf(sc - mn);
        float vl   = qkv[basek + (size_t)s * 1536 + 512];
        l   = l * corr + p;
        acc = acc * corr + p * vl;
        m = mn;
    }
    qkv[rowq] = acc / l;
}

// ---------------------------------------------------------------------------
// out = xn2 + b2 (broadcast); FFN2 chunks then accumulate into out.
__global__ __launch_bounds__(256) void init_out_kernel(const float* __restrict__ xn2,
        const float* __restrict__ b2, float* __restrict__ out) {
    int idx = blockIdx.x * 256 + threadIdx.x;
    out[idx] = xn2[idx] + b2[idx & 511];
}

// ---------------------------------------------------------------------------
extern "C" void kernel_launch(void* const* d_in, const int* in_sizes, int n_in,
                              void* d_out, int out_size, void* d_ws, size_t ws_size,
                              hipStream_t stream) {
    const float* x   = (const float*)d_in[0];
    const float* Wq  = (const float*)d_in[1];
    const float* Wk  = (const float*)d_in[2];
    const float* Wv  = (const float*)d_in[3];
    const float* Wo  = (const float*)d_in[4];
    const float* bo  = (const float*)d_in[5];
    const float* W1  = (const float*)d_in[6];
    const float* b1  = (const float*)d_in[7];
    const float* W2  = (const float*)d_in[8];
    const float* b2  = (const float*)d_in[9];
    const float* g1  = (const float*)d_in[10];
    const float* be1 = (const float*)d_in[11];
    const float* g2  = (const float*)d_in[12];
    const float* be2 = (const float*)d_in[13];
    float* out = (float*)d_out;

    // Workspace layout (floats). Total = 25,952,256 floats = ~104 MB.
    float* ws  = (float*)d_ws;
    float* xn  = ws;                 // [8192, 512]   LN1 output (kept for residual)
    float* x2  = ws + 4194304;       // [8192, 512]   xn + mha, then xn2 in place
    float* qkv = ws + 8388608;       // [8192, 1536]  q|k|v packed; q slot becomes attn out
    float* hch = ws + 20971520;      // [8192, 512]   FFN hidden chunk
    float* bq  = ws + 25165824;      // [512, 1536]   repacked QKV weights

    // 1. xn = LN(x, g1, be1)
    ln_kernel<<<Mrows, 256, 0, stream>>>(x, g1, be1, xn);
    // 2. repack weights, qkv = xn @ Bqkv   (single GEMM, N=1536)
    repack_qkv<<<(512 * 1536) / 256, 256, 0, stream>>>(Wq, Wk, Wv, bq);
    gemm_kernel<<<dim3(1536 / 64, Mrows / 64), 256, 0, stream>>>(
        xn, 512, bq, 1536, qkv, 1536, 512, nullptr, nullptr, 0);
    // 3. causal attention (writes o over the q slot)
    attn_kernel<<<(Bsz * Hh * Tt) / 4, 256, 0, stream>>>(qkv);
    // 4. x2 = xn + o @ Wo + bo
    gemm_kernel<<<dim3(512 / 64, Mrows / 64), 256, 0, stream>>>(
        qkv, 1536, Wo, 512, x2, 512, 512, bo, xn, 1);
    // 5. xn2 = LN(x2, g2, be2) in place
    ln_kernel<<<Mrows, 256, 0, stream>>>(x2, g2, be2, x2);
    // 6. out = xn2 + b2; then accumulate relu(xn2@W1+b1)@W2 in HID chunks of 512
    init_out_kernel<<<(Mrows * Ee) / 256, 256, 0, stream>>>(x2, b2, out);
    for (int c0 = 0; c0 < HIDs; c0 += 512) {
        gemm_kernel<<<dim3(8, Mrows / 64), 256, 0, stream>>>(
            x2, 512, W1 + c0, HIDs, hch, 512, 512, b1 + c0, nullptr, 2);
        gemm_kernel<<<dim3(8, Mrows / 64), 256, 0, stream>>>(
            hch, 512, W2 + (size_t)c0 * 512, 512, out, 512, 512, nullptr, nullptr, 3);
    }
}

// Round 2
// 2407.909 us; speedup vs baseline: 2.5827x; 2.5827x over previous
//
#include <hip/hip_runtime.h>
#include <math.h>

// Problem constants (B,T,E)=(4,2048,512), H=8, D=64, HID=H*E=4096.
#define Bsz 4
#define Tt 2048
#define Ee 512
#define Hh 8
#define Dd 64
#define HIDs 4096
#define Mrows (Bsz * Tt)   // 8192 token rows

// ---------------------------------------------------------------------------
// LayerNorm: one 256-thread block per row of 512. Safe in-place (row values
// are held in registers before any write).
__global__ __launch_bounds__(256) void ln_kernel(const float* __restrict__ x,
        const float* __restrict__ g, const float* __restrict__ b,
        float* __restrict__ out) {
    int row = blockIdx.x;
    int tid = threadIdx.x;
    const float* xr = x + (size_t)row * Ee;
    float v0 = xr[tid];
    float v1 = xr[tid + 256];
    float s = v0 + v1;
    float sq = v0 * v0 + v1 * v1;
#pragma unroll
    for (int off = 32; off > 0; off >>= 1) {
        s  += __shfl_xor(s, off, 64);
        sq += __shfl_xor(sq, off, 64);
    }
    __shared__ float ls[4], lq[4];
    int wid = tid >> 6, lane = tid & 63;
    if (lane == 0) { ls[wid] = s; lq[wid] = sq; }
    __syncthreads();
    s  = ls[0] + ls[1] + ls[2] + ls[3];
    sq = lq[0] + lq[1] + lq[2] + lq[3];
    float mean = s * (1.0f / Ee);
    float var  = sq * (1.0f / Ee) - mean * mean;   // biased var, like jnp.var
    float rstd = rsqrtf(var + 1e-5f);
    float* orow = out + (size_t)row * Ee;
    orow[tid]       = (v0 - mean) * rstd * g[tid]       + b[tid];
    orow[tid + 256] = (v1 - mean) * rstd * g[tid + 256] + b[tid + 256];
}

// ---------------------------------------------------------------------------
// Repack Wq/Wk/Wv [H,E,D] into one plain row-major [E, 3*H*D] B-matrix.
__global__ __launch_bounds__(256) void repack_qkv(const float* __restrict__ Wq,
        const float* __restrict__ Wk, const float* __restrict__ Wv,
        float* __restrict__ bq) {
    int idx = blockIdx.x * 256 + threadIdx.x;   // < 512*1536
    int e  = idx / 1536;
    int c  = idx % 1536;
    int p  = c >> 9;        // 0=q,1=k,2=v
    int pp = c & 511;
    int h  = pp >> 6;
    int d  = pp & 63;
    const float* W = (p == 0) ? Wq : ((p == 1) ? Wk : Wv);
    bq[idx] = W[(h * Ee + e) * Dd + d];
}

// ---------------------------------------------------------------------------
// fp32 tiled GEMM, 64x64 tile, BK=16, 4x4 per thread. Epilogue modes:
//   0: C = acc
//   1: C = resid + acc + bias[c]        (Wo projection + residual)
//   2: C = relu(acc + bias[c])          (FFN layer 1 chunk)
//   3: C += acc                         (FFN layer 2 chunk accumulate)
__global__ __launch_bounds__(256) void gemm_kernel(
        const float* __restrict__ A, int lda,
        const float* __restrict__ Bm, int ldb,
        float* __restrict__ C, int ldc, int K,
        const float* __restrict__ bias,
        const float* __restrict__ resid, int mode) {
    __shared__ float As[16][64];   // As[k][m]
    __shared__ float Bs[16][64];   // Bs[k][n]
    int tid  = threadIdx.x;
    int row0 = blockIdx.y * 64;
    int col0 = blockIdx.x * 64;
    int tx = tid & 15;             // 4-col group
    int ty = tid >> 4;             // 4-row group
    int a_m = tid >> 2;            // 0..63
    int a_k = (tid & 3) << 2;      // 0,4,8,12
    int b_k = tid >> 4;            // 0..15
    int b_n = (tid & 15) << 2;     // 0..60
    float acc[4][4] = {};
    for (int k0 = 0; k0 < K; k0 += 16) {
        float4 av = *(const float4*)(A + (size_t)(row0 + a_m) * lda + k0 + a_k);
        As[a_k + 0][a_m] = av.x;
        As[a_k + 1][a_m] = av.y;
        As[a_k + 2][a_m] = av.z;
        As[a_k + 3][a_m] = av.w;
        *(float4*)(&Bs[b_k][b_n]) =
            *(const float4*)(Bm + (size_t)(k0 + b_k) * ldb + col0 + b_n);
        __syncthreads();
#pragma unroll
        for (int kk = 0; kk < 16; ++kk) {
            float4 a4 = *(const float4*)(&As[kk][ty << 2]);
            float4 b4 = *(const float4*)(&Bs[kk][tx << 2]);
            float a_[4] = {a4.x, a4.y, a4.z, a4.w};
            float b_[4] = {b4.x, b4.y, b4.z, b4.w};
#pragma unroll
            for (int i = 0; i < 4; ++i)
#pragma unroll
                for (int j = 0; j < 4; ++j)
                    acc[i][j] = fmaf(a_[i], b_[j], acc[i][j]);
        }
        __syncthreads();
    }
#pragma unroll
    for (int i = 0; i < 4; ++i) {
        int r = row0 + (ty << 2) + i;
#pragma unroll
        for (int j = 0; j < 4; ++j) {
            int c = col0 + (tx << 2) + j;
            float v = acc[i][j];
            size_t ci = (size_t)r * ldc + c;
            if (mode == 0) {
                C[ci] = v;
            } else if (mode == 1) {
                C[ci] = resid[ci] + v + bias[c];
            } else if (mode == 2) {
                float vv = v + bias[c];
                C[ci] = vv > 0.0f ? vv : 0.0f;
            } else {
                C[ci] += v;
            }
        }
    }
}

// ---------------------------------------------------------------------------
// Flash-style causal attention, fp32. One block = 8 consecutive Q rows of one
// (b,h); 4 waves x 2 rows each. Iterates over 64-wide S tiles; K^T and V are
// staged in LDS. Two lane roles per tile:
//   QK phase: lane = s. sc_s = sum_d Kt[d][lane] * Q[row][d] (Q broadcast).
//   PV phase: lane = d. acc_d += P[s] * Vs[s][lane] (P broadcast).
// Online softmax state (m,l) is wave-uniform per row. Output overwrites the
// q slot of the packed qkv buffer (only this block's waves touch those rows).
__global__ __launch_bounds__(256) void attn_kernel(float* __restrict__ qkv) {
    __shared__ float Kt[64][65];      // [d][s], stride 65: reads+writes 2-way (free)
    __shared__ float Vs[64][68];      // [s][d], stride 68: float4-aligned staging
    __shared__ float Qs[64][8];       // [d][row_local]
    __shared__ float Ps[4][64][2];    // [wave][s][row_pair]
    int tid  = threadIdx.x;
    int wave = tid >> 6, lane = tid & 63;
    int blk = blockIdx.x;
    int bh  = blk >> 8;               // T/8 = 256 q-blocks per (b,h)
    int qb  = blk & 255;
    int b = bh >> 3, h = bh & 7;
    int base = qb * 8;
    size_t rowbase = (size_t)(b * Tt) * 1536;
    int qoff = h * 64;
    int koff = 512 + h * 64;
    int voff = 1024 + h * 64;

    // stage the 8 Q rows into Qs[d][r]
    {
        int r  = tid >> 5;            // 0..7
        int d0 = (tid & 31) * 2;      // 0..62
        float2 q2 = *(const float2*)(qkv + rowbase + (size_t)(base + r) * 1536 + qoff + d0);
        Qs[d0][r]     = q2.x;
        Qs[d0 + 1][r] = q2.y;
    }

    int r0 = base + wave * 2;
    int r1 = r0 + 1;
    float m0 = -1e30f, l0 = 0.f, m1 = -1e30f, l1 = 0.f;
    float acc0 = 0.f, acc1 = 0.f;     // lane = d
    const float scale = 0.022097086912079608f;   // T**-0.5 per reference

    int tlast = base >> 6;            // final (masked) tile index
    for (int tile = 0; tile <= tlast; ++tile) {
        int s0 = tile << 6;
        __syncthreads();              // previous tile's LDS reads done
        // stage K (transposed) and V tiles; 4 passes of 16 s-rows
#pragma unroll
        for (int pp = 0; pp < 4; ++pp) {
            int si = (tid >> 4) + pp * 16;
            int d  = (tid & 15) * 4;
            size_t g = rowbase + (size_t)(s0 + si) * 1536;
            float4 k4 = *(const float4*)(qkv + g + koff + d);
            Kt[d][si] = k4.x; Kt[d+1][si] = k4.y; Kt[d+2][si] = k4.z; Kt[d+3][si] = k4.w;
            float4 v4 = *(const float4*)(qkv + g + voff + d);
            *(float4*)(&Vs[si][d]) = v4;
        }
        __syncthreads();
        // ---- QK phase: lane = s
        float sc0 = 0.f, sc1 = 0.f;
#pragma unroll 16
        for (int d = 0; d < 64; ++d) {
            float kd = Kt[d][lane];
            float2 q2 = *(const float2*)(&Qs[d][wave * 2]);
            sc0 = fmaf(kd, q2.x, sc0);
            sc1 = fmaf(kd, q2.y, sc1);
        }
        sc0 *= scale; sc1 *= scale;
        if (tile == tlast) {          // causal mask, only final tile partial
            int sg = s0 + lane;
            if (sg > r0) sc0 = -1e30f;
            if (sg > r1) sc1 = -1e30f;
        }
        // ---- online softmax (per-tile wave reductions)
        float mt0 = sc0, mt1 = sc1;
#pragma unroll
        for (int off = 32; off > 0; off >>= 1) {
            mt0 = fmaxf(mt0, __shfl_xor(mt0, off, 64));
            mt1 = fmaxf(mt1, __shfl_xor(mt1, off, 64));
        }
        float mn0 = fmaxf(m0, mt0), mn1 = fmaxf(m1, mt1);
        float p0 = __expf(sc0 - mn0);
        float p1 = __expf(sc1 - mn1);
        float sum0 = p0, sum1 = p1;
#pragma unroll
        for (int off = 32; off > 0; off >>= 1) {
            sum0 += __shfl_xor(sum0, off, 64);
            sum1 += __shfl_xor(sum1, off, 64);
        }
        float c0 = __expf(m0 - mn0), c1 = __expf(m1 - mn1);
        l0 = l0 * c0 + sum0; l1 = l1 * c1 + sum1;
        m0 = mn0; m1 = mn1;
        Ps[wave][lane][0] = p0;
        Ps[wave][lane][1] = p1;
        // ---- PV phase: lane = d  (same-wave LDS producer/consumer, no barrier)
        acc0 *= c0; acc1 *= c1;
#pragma unroll 16
        for (int s = 0; s < 64; ++s) {
            float vd = Vs[s][lane];
            float2 p2 = *(const float2*)(&Ps[wave][s][0]);
            acc0 = fmaf(p2.x, vd, acc0);
            acc1 = fmaf(p2.y, vd, acc1);
        }
    }
    // epilogue: write attention output over the q slot
    qkv[rowbase + (size_t)r0 * 1536 + qoff + lane] = acc0 / l0;
    qkv[rowbase + (size_t)r1 * 1536 + qoff + lane] = acc1 / l1;
}

// ---------------------------------------------------------------------------
// out = xn2 + b2 (broadcast); FFN2 chunks then accumulate into out.
__global__ __launch_bounds__(256) void init_out_kernel(const float* __restrict__ xn2,
        const float* __restrict__ b2, float* __restrict__ out) {
    int idx = blockIdx.x * 256 + threadIdx.x;
    out[idx] = xn2[idx] + b2[idx & 511];
}

// ---------------------------------------------------------------------------
extern "C" void kernel_launch(void* const* d_in, const int* in_sizes, int n_in,
                              void* d_out, int out_size, void* d_ws, size_t ws_size,
                              hipStream_t stream) {
    const float* x   = (const float*)d_in[0];
    const float* Wq  = (const float*)d_in[1];
    const float* Wk  = (const float*)d_in[2];
    const float* Wv  = (const float*)d_in[3];
    const float* Wo  = (const float*)d_in[4];
    const float* bo  = (const float*)d_in[5];
    const float* W1  = (const float*)d_in[6];
    const float* b1  = (const float*)d_in[7];
    const float* W2  = (const float*)d_in[8];
    const float* b2  = (const float*)d_in[9];
    const float* g1  = (const float*)d_in[10];
    const float* be1 = (const float*)d_in[11];
    const float* g2  = (const float*)d_in[12];
    const float* be2 = (const float*)d_in[13];
    float* out = (float*)d_out;

    // Workspace layout (floats). Total = 25,952,256 floats = ~104 MB.
    float* ws  = (float*)d_ws;
    float* xn  = ws;                 // [8192, 512]   LN1 output (kept for residual)
    float* x2  = ws + 4194304;       // [8192, 512]   xn + mha, then xn2 in place
    float* qkv = ws + 8388608;       // [8192, 1536]  q|k|v packed; q slot becomes attn out
    float* hch = ws + 20971520;      // [8192, 512]   FFN hidden chunk
    float* bq  = ws + 25165824;      // [512, 1536]   repacked QKV weights

    // 1. xn = LN(x, g1, be1)
    ln_kernel<<<Mrows, 256, 0, stream>>>(x, g1, be1, xn);
    // 2. repack weights, qkv = xn @ Bqkv   (single GEMM, N=1536)
    repack_qkv<<<(512 * 1536) / 256, 256, 0, stream>>>(Wq, Wk, Wv, bq);
    gemm_kernel<<<dim3(1536 / 64, Mrows / 64), 256, 0, stream>>>(
        xn, 512, bq, 1536, qkv, 1536, 512, nullptr, nullptr, 0);
    // 3. causal attention (flash-style, writes o over the q slot)
    attn_kernel<<<Bsz * Hh * (Tt / 8), 256, 0, stream>>>(qkv);
    // 4. x2 = xn + o @ Wo + bo
    gemm_kernel<<<dim3(512 / 64, Mrows / 64), 256, 0, stream>>>(
        qkv, 1536, Wo, 512, x2, 512, 512, bo, xn, 1);
    // 5. xn2 = LN(x2, g2, be2) in place
    ln_kernel<<<Mrows, 256, 0, stream>>>(x2, g2, be2, x2);
    // 6. out = xn2 + b2; then accumulate relu(xn2@W1+b1)@W2 in HID chunks of 512
    init_out_kernel<<<(Mrows * Ee) / 256, 256, 0, stream>>>(x2, b2, out);
    for (int c0 = 0; c0 < HIDs; c0 += 512) {
        gemm_kernel<<<dim3(8, Mrows / 64), 256, 0, stream>>>(
            x2, 512, W1 + c0, HIDs, hch, 512, 512, b1 + c0, nullptr, 2);
        gemm_kernel<<<dim3(8, Mrows / 64), 256, 0, stream>>>(
            hch, 512, W2 + (size_t)c0 * 512, 512, out, 512, 512, nullptr, nullptr, 3);
    }
}

// Round 3
// 1571.557 us; speedup vs baseline: 3.9572x; 1.5322x over previous
//
#include <hip/hip_runtime.h>
#include <hip/hip_bf16.h>
#include <math.h>

// Problem constants (B,T,E)=(4,2048,512), H=8, D=64, HID=H*E=4096.
#define Bsz 4
#define Tt 2048
#define Ee 512
#define Hh 8
#define Dd 64
#define HIDs 4096
#define Mrows (Bsz * Tt)   // 8192 token rows
#define HC 1024            // FFN hidden chunk

typedef __attribute__((ext_vector_type(8))) short short8;   // 8 bf16 (4 VGPRs)
typedef __attribute__((ext_vector_type(4))) float f32x4;    // MFMA accumulator

__device__ __forceinline__ float bf_lo(unsigned int u) { return __uint_as_float(u << 16); }
__device__ __forceinline__ float bf_hi(unsigned int u) { return __uint_as_float(u & 0xffff0000u); }

// ---------------------------------------------------------------------------
// LayerNorm: one 256-thread block per row of 512. Writes fp32 + bf16 copies.
// Safe in-place on the fp32 buffer (row held in registers before writes).
__global__ __launch_bounds__(256) void ln_kernel(const float* __restrict__ x,
        const float* __restrict__ g, const float* __restrict__ b,
        float* __restrict__ out, __hip_bfloat16* __restrict__ out_bf) {
    int row = blockIdx.x;
    int tid = threadIdx.x;
    const float* xr = x + (size_t)row * Ee;
    float v0 = xr[tid];
    float v1 = xr[tid + 256];
    float s = v0 + v1;
    float sq = v0 * v0 + v1 * v1;
#pragma unroll
    for (int off = 32; off > 0; off >>= 1) {
        s  += __shfl_xor(s, off, 64);
        sq += __shfl_xor(sq, off, 64);
    }
    __shared__ float ls[4], lq[4];
    int wid = tid >> 6, lane = tid & 63;
    if (lane == 0) { ls[wid] = s; lq[wid] = sq; }
    __syncthreads();
    s  = ls[0] + ls[1] + ls[2] + ls[3];
    sq = lq[0] + lq[1] + lq[2] + lq[3];
    float mean = s * (1.0f / Ee);
    float var  = sq * (1.0f / Ee) - mean * mean;   // biased var, like jnp.var
    float rstd = rsqrtf(var + 1e-5f);
    float o0 = (v0 - mean) * rstd * g[tid]       + b[tid];
    float o1 = (v1 - mean) * rstd * g[tid + 256] + b[tid + 256];
    float* orow = out + (size_t)row * Ee;
    orow[tid]       = o0;
    orow[tid + 256] = o1;
    __hip_bfloat16* brow = out_bf + (size_t)row * Ee;
    brow[tid]       = __float2bfloat16(o0);
    brow[tid + 256] = __float2bfloat16(o1);
}

// ---------------------------------------------------------------------------
// Generic fp32 [R][C] -> bf16 [C][R] transpose, 64x64 LDS tiles.
__global__ __launch_bounds__(256) void transpose_bf16(const float* __restrict__ in,
        __hip_bfloat16* __restrict__ outp, int R, int C) {
    __shared__ float tile[64][65];
    int c0 = blockIdx.x * 64, r0 = blockIdx.y * 64;
    int tc = threadIdx.x & 63, tg = threadIdx.x >> 6;
#pragma unroll
    for (int i = 0; i < 16; ++i) {
        int r = tg * 16 + i;
        tile[r][tc] = in[(size_t)(r0 + r) * C + c0 + tc];
    }
    __syncthreads();
#pragma unroll
    for (int i = 0; i < 16; ++i) {
        int cc = tg * 16 + i;
        outp[(size_t)(c0 + cc) * R + r0 + tc] = __float2bfloat16(tile[tc][cc]);
    }
}

// ---------------------------------------------------------------------------
// Repack Wq/Wk/Wv [H,E,D] fp32 -> bqT [3*H*D][E] bf16 (row c=p*512+h*64+d).
// One block per (p, h, 64-wide e-tile): LDS transpose of a [64e][64d] tile.
__global__ __launch_bounds__(256) void repack_qkv_t(const float* __restrict__ Wq,
        const float* __restrict__ Wk, const float* __restrict__ Wv,
        __hip_bfloat16* __restrict__ bqT) {
    int blk = blockIdx.x;            // p*64 + h*8 + et
    int p = blk >> 6, h = (blk >> 3) & 7, et = blk & 7;
    const float* W = (p == 0) ? Wq : ((p == 1) ? Wk : Wv);
    __shared__ float tile[64][65];
    int td = threadIdx.x & 63, tg = threadIdx.x >> 6;
#pragma unroll
    for (int i = 0; i < 16; ++i) {
        int e = tg * 16 + i;
        tile[e][td] = W[((size_t)h * Ee + et * 64 + e) * Dd + td];
    }
    __syncthreads();
#pragma unroll
    for (int i = 0; i < 16; ++i) {
        int d = tg * 16 + i;
        bqT[((size_t)(p * 512 + h * 64 + d)) * Ee + et * 64 + td] = __float2bfloat16(tile[td][d]);
    }
}

// ---------------------------------------------------------------------------
// bf16 MFMA GEMM (m97 recipe): 128x128 tile, BK=32, global_load_lds width 16,
// 2x2 waves x (4x4 of 16x16x32 MFMA). A [M][K] bf16 row-major, B [N][K] bf16
// row-major (i.e. B^T). Epilogue modes:
//   0: Cb = bf16(acc)                    (QKV projection)
//   1: Cf = Cf + acc + bias[c]           (Wo: residual add in place)
//   2: Cb = bf16(relu(acc + bias[c]))    (FFN1 chunk)
//   3: Cf += acc                         (FFN2 chunk accumulate)
__global__ __launch_bounds__(256) void mfma_gemm(
        const __hip_bfloat16* __restrict__ A, int lda,
        const __hip_bfloat16* __restrict__ B, int ldb,
        float* __restrict__ Cf, __hip_bfloat16* __restrict__ Cb, int ldc, int K,
        const float* __restrict__ bias, int mode) {
    __shared__ __hip_bfloat16 As[128 * 32];   // [m][k], rows of 32 contiguous
    __shared__ __hip_bfloat16 Bs[128 * 32];   // [n][k]
    int tid = threadIdx.x;
    int lane = tid & 63, wave = tid >> 6;
    int wm = wave >> 1, wn = wave & 1;
    int row0 = blockIdx.y * 128, col0 = blockIdx.x * 128;
    f32x4 acc[4][4];
#pragma unroll
    for (int i = 0; i < 4; ++i)
#pragma unroll
        for (int j = 0; j < 4; ++j) acc[i][j] = (f32x4){0.f, 0.f, 0.f, 0.f};

    int fr = lane & 15;
    int kq = (lane >> 4) << 3;            // fragment k-offset: 0/8/16/24

    for (int k0 = 0; k0 < K; k0 += 32) {
        __syncthreads();                  // prior tile's LDS reads complete
#pragma unroll
        for (int j = 0; j < 2; ++j) {
            int c  = j * 256 + tid;               // 16B chunk id (per-lane)
            int cb = j * 256 + wave * 64;         // wave-uniform LDS base chunk
            int r  = c >> 2, kg = (c & 3) << 3;
            __builtin_amdgcn_global_load_lds(
                (const __attribute__((address_space(1))) void*)(A + (size_t)(row0 + r) * lda + k0 + kg),
                (__attribute__((address_space(3))) void*)(As + cb * 8), 16, 0, 0);
            __builtin_amdgcn_global_load_lds(
                (const __attribute__((address_space(1))) void*)(B + (size_t)(col0 + r) * ldb + k0 + kg),
                (__attribute__((address_space(3))) void*)(Bs + cb * 8), 16, 0, 0);
        }
        __syncthreads();                  // staging visible to all waves
        short8 afr[4], bfr[4];
#pragma unroll
        for (int i = 0; i < 4; ++i) {
            afr[i] = *(const short8*)(As + (wm * 64 + i * 16 + fr) * 32 + kq);
            bfr[i] = *(const short8*)(Bs + (wn * 64 + i * 16 + fr) * 32 + kq);
        }
#pragma unroll
        for (int i = 0; i < 4; ++i)
#pragma unroll
            for (int j = 0; j < 4; ++j)
                acc[i][j] = __builtin_amdgcn_mfma_f32_16x16x32_bf16(afr[i], bfr[j], acc[i][j], 0, 0, 0);
    }
    // epilogue: C/D layout col=lane&15, row=(lane>>4)*4+reg
    int rq = (lane >> 4) << 2;
#pragma unroll
    for (int i = 0; i < 4; ++i) {
#pragma unroll
        for (int j = 0; j < 4; ++j) {
#pragma unroll
            for (int gidx = 0; gidx < 4; ++gidx) {
                int r = row0 + wm * 64 + i * 16 + rq + gidx;
                int c = col0 + wn * 64 + j * 16 + fr;
                size_t ci = (size_t)r * ldc + c;
                float v = acc[i][j][gidx];
                if (mode == 0) {
                    Cb[ci] = __float2bfloat16(v);
                } else if (mode == 1) {
                    Cf[ci] = Cf[ci] + v + bias[c];
                } else if (mode == 2) {
                    float t = v + bias[c];
                    Cb[ci] = __float2bfloat16(t > 0.f ? t : 0.f);
                } else {
                    Cf[ci] += v;
                }
            }
        }
    }
}

// ---------------------------------------------------------------------------
// Flash-style causal attention, bf16 in/out, fp32 math. One block = 8 Q rows
// of one (b,h); 4 waves x 2 rows. 64-wide S tiles staged in LDS (fp32).
// QK phase lane=s, PV phase lane=d; fma chains split 4-way for ILP.
__global__ __launch_bounds__(256) void attn_kernel(const __hip_bfloat16* __restrict__ qkvb,
        __hip_bfloat16* __restrict__ ob) {
    __shared__ float Kt[64][65];      // [d][s]
    __shared__ float Vs[64][68];      // [s][d]
    __shared__ float Qs[64][8];       // [d][row_local]
    __shared__ float Ps[4][64][2];    // [wave][s][row_pair]
    const unsigned short* q16 = (const unsigned short*)qkvb;
    int tid  = threadIdx.x;
    int wave = tid >> 6, lane = tid & 63;
    int blk = blockIdx.x;
    int bh  = blk >> 8, qb = blk & 255;
    int b = bh >> 3, h = bh & 7;
    int base = qb * 8;
    size_t rowbase = (size_t)(b * Tt) * 1536;
    int qoff = h * 64;
    int koff = 512 + h * 64;
    int voff = 1024 + h * 64;

    {   // stage the 8 Q rows into Qs[d][r]
        int r  = tid >> 5;
        int d0 = (tid & 31) * 2;
        unsigned int q2 = *(const unsigned int*)(q16 + rowbase + (size_t)(base + r) * 1536 + qoff + d0);
        Qs[d0][r]     = bf_lo(q2);
        Qs[d0 + 1][r] = bf_hi(q2);
    }

    int r0 = base + wave * 2;
    int r1 = r0 + 1;
    float m0 = -1e30f, l0 = 0.f, m1 = -1e30f, l1 = 0.f;
    float acc0 = 0.f, acc1 = 0.f;     // lane = d
    const float scale = 0.022097086912079608f;   // T**-0.5 per reference

    int tlast = base >> 6;
    for (int tile = 0; tile <= tlast; ++tile) {
        int s0 = tile << 6;
        __syncthreads();
#pragma unroll
        for (int pp = 0; pp < 4; ++pp) {
            int si = (tid >> 4) + pp * 16;
            int d  = (tid & 15) * 4;
            size_t gb = rowbase + (size_t)(s0 + si) * 1536;
            uint2 k2 = *(const uint2*)(q16 + gb + koff + d);
            Kt[d][si]     = bf_lo(k2.x);
            Kt[d + 1][si] = bf_hi(k2.x);
            Kt[d + 2][si] = bf_lo(k2.y);
            Kt[d + 3][si] = bf_hi(k2.y);
            uint2 v2 = *(const uint2*)(q16 + gb + voff + d);
            Vs[si][d]     = bf_lo(v2.x);
            Vs[si][d + 1] = bf_hi(v2.x);
            Vs[si][d + 2] = bf_lo(v2.y);
            Vs[si][d + 3] = bf_hi(v2.y);
        }
        __syncthreads();
        // ---- QK phase: lane = s, 4 independent chains per row
        float s00 = 0.f, s01 = 0.f, s02 = 0.f, s03 = 0.f;
        float s10 = 0.f, s11 = 0.f, s12 = 0.f, s13 = 0.f;
#pragma unroll
        for (int d = 0; d < 16; ++d) {
            float k0v = Kt[d][lane];
            float k1v = Kt[d + 16][lane];
            float k2v = Kt[d + 32][lane];
            float k3v = Kt[d + 48][lane];
            float2 qa = *(const float2*)(&Qs[d][wave * 2]);
            float2 qb2 = *(const float2*)(&Qs[d + 16][wave * 2]);
            float2 qc = *(const float2*)(&Qs[d + 32][wave * 2]);
            float2 qd = *(const float2*)(&Qs[d + 48][wave * 2]);
            s00 = fmaf(k0v, qa.x, s00);  s10 = fmaf(k0v, qa.y, s10);
            s01 = fmaf(k1v, qb2.x, s01); s11 = fmaf(k1v, qb2.y, s11);
            s02 = fmaf(k2v, qc.x, s02);  s12 = fmaf(k2v, qc.y, s12);
            s03 = fmaf(k3v, qd.x, s03);  s13 = fmaf(k3v, qd.y, s13);
        }
        float sc0 = ((s00 + s01) + (s02 + s03)) * scale;
        float sc1 = ((s10 + s11) + (s12 + s13)) * scale;
        if (tile == tlast) {
            int sg = s0 + lane;
            if (sg > r0) sc0 = -1e30f;
            if (sg > r1) sc1 = -1e30f;
        }
        // ---- online softmax
        float mt0 = sc0, mt1 = sc1;
#pragma unroll
        for (int off = 32; off > 0; off >>= 1) {
            mt0 = fmaxf(mt0, __shfl_xor(mt0, off, 64));
            mt1 = fmaxf(mt1, __shfl_xor(mt1, off, 64));
        }
        float mn0 = fmaxf(m0, mt0), mn1 = fmaxf(m1, mt1);
        float p0 = __expf(sc0 - mn0);
        float p1 = __expf(sc1 - mn1);
        float sum0 = p0, sum1 = p1;
#pragma unroll
        for (int off = 32; off > 0; off >>= 1) {
            sum0 += __shfl_xor(sum0, off, 64);
            sum1 += __shfl_xor(sum1, off, 64);
        }
        float c0 = __expf(m0 - mn0), c1 = __expf(m1 - mn1);
        l0 = l0 * c0 + sum0; l1 = l1 * c1 + sum1;
        m0 = mn0; m1 = mn1;
        Ps[wave][lane][0] = p0;
        Ps[wave][lane][1] = p1;
        // ---- PV phase: lane = d, 4 independent chains per row
        float a0 = 0.f, a1 = 0.f, a2 = 0.f, a3 = 0.f;
        float b0 = 0.f, b1 = 0.f, b2 = 0.f, b3 = 0.f;
#pragma unroll
        for (int s = 0; s < 16; ++s) {
            float v0v = Vs[s][lane];
            float v1v = Vs[s + 16][lane];
            float v2v = Vs[s + 32][lane];
            float v3v = Vs[s + 48][lane];
            float2 p0v = *(const float2*)(&Ps[wave][s][0]);
            float2 p1v = *(const float2*)(&Ps[wave][s + 16][0]);
            float2 p2v = *(const float2*)(&Ps[wave][s + 32][0]);
            float2 p3v = *(const float2*)(&Ps[wave][s + 48][0]);
            a0 = fmaf(p0v.x, v0v, a0);  b0 = fmaf(p0v.y, v0v, b0);
            a1 = fmaf(p1v.x, v1v, a1);  b1 = fmaf(p1v.y, v1v, b1);
            a2 = fmaf(p2v.x, v2v, a2);  b2 = fmaf(p2v.y, v2v, b2);
            a3 = fmaf(p3v.x, v3v, a3);  b3 = fmaf(p3v.y, v3v, b3);
        }
        acc0 = acc0 * c0 + ((a0 + a1) + (a2 + a3));
        acc1 = acc1 * c1 + ((b0 + b1) + (b2 + b3));
    }
    ob[(size_t)(b * Tt + r0) * 512 + h * 64 + lane] = __float2bfloat16(acc0 / l0);
    ob[(size_t)(b * Tt + r1) * 512 + h * 64 + lane] = __float2bfloat16(acc1 / l1);
}

// ---------------------------------------------------------------------------
// out = xn2 + b2 (broadcast); FFN2 chunks then accumulate into out.
__global__ __launch_bounds__(256) void init_out_kernel(const float* __restrict__ xn2,
        const float* __restrict__ b2, float* __restrict__ out) {
    int idx = blockIdx.x * 256 + threadIdx.x;
    out[idx] = xn2[idx] + b2[idx & 511];
}

// ---------------------------------------------------------------------------
extern "C" void kernel_launch(void* const* d_in, const int* in_sizes, int n_in,
                              void* d_out, int out_size, void* d_ws, size_t ws_size,
                              hipStream_t stream) {
    const float* x   = (const float*)d_in[0];
    const float* Wq  = (const float*)d_in[1];
    const float* Wk  = (const float*)d_in[2];
    const float* Wv  = (const float*)d_in[3];
    const float* Wo  = (const float*)d_in[4];
    const float* bo  = (const float*)d_in[5];
    const float* W1  = (const float*)d_in[6];
    const float* b1  = (const float*)d_in[7];
    const float* W2  = (const float*)d_in[8];
    const float* b2  = (const float*)d_in[9];
    const float* g1  = (const float*)d_in[10];
    const float* be1 = (const float*)d_in[11];
    const float* g2  = (const float*)d_in[12];
    const float* be2 = (const float*)d_in[13];
    float* out = (float*)d_out;

    // Workspace layout (byte offsets, all 16B-aligned). Total ~86 MB.
    char* ws = (char*)d_ws;
    float*          xn     = (float*)(ws);                           // [8192][512] fp32 (residual; becomes x2 then xn2 in place)
    __hip_bfloat16* xn_bf  = (__hip_bfloat16*)(ws + 16777216);       // [8192][512] bf16 (LN out for GEMM A; reused for LN2)
    __hip_bfloat16* qkv_bf = (__hip_bfloat16*)(ws + 25165824);       // [8192][1536] bf16
    __hip_bfloat16* o_bf   = (__hip_bfloat16*)(ws + 50331648);       // [8192][512] bf16
    __hip_bfloat16* h_bf   = (__hip_bfloat16*)(ws + 58720256);       // [8192][HC] bf16
    __hip_bfloat16* bqT    = (__hip_bfloat16*)(ws + 75497472);       // [1536][512] bf16
    __hip_bfloat16* woT    = (__hip_bfloat16*)(ws + 77070336);       // [512][512] bf16
    __hip_bfloat16* w1T    = (__hip_bfloat16*)(ws + 77594624);       // [4096][512] bf16
    __hip_bfloat16* w2T    = (__hip_bfloat16*)(ws + 81788928);       // [512][4096] bf16

    // 1. xn = LN(x, g1, be1)  (fp32 + bf16)
    ln_kernel<<<Mrows, 256, 0, stream>>>(x, g1, be1, xn, xn_bf);
    // 2. weight repacks to bf16 [N][K]
    repack_qkv_t<<<192, 256, 0, stream>>>(Wq, Wk, Wv, bqT);
    transpose_bf16<<<dim3(8, 8),  256, 0, stream>>>(Wo, woT, 512, 512);
    transpose_bf16<<<dim3(64, 8), 256, 0, stream>>>(W1, w1T, 512, HIDs);
    transpose_bf16<<<dim3(8, 64), 256, 0, stream>>>(W2, w2T, HIDs, 512);
    // 3. qkv = xn @ Wqkv  -> bf16
    mfma_gemm<<<dim3(1536 / 128, Mrows / 128), 256, 0, stream>>>(
        xn_bf, 512, bqT, 512, nullptr, qkv_bf, 1536, 512, nullptr, 0);
    // 4. causal attention -> o_bf
    attn_kernel<<<Bsz * Hh * (Tt / 8), 256, 0, stream>>>(qkv_bf, o_bf);
    // 5. xn(=x2) = xn + o @ Wo + bo   (in-place residual add)
    mfma_gemm<<<dim3(512 / 128, Mrows / 128), 256, 0, stream>>>(
        o_bf, 512, woT, 512, xn, nullptr, 512, 512, bo, 1);
    // 6. xn(=xn2) = LN(x2, g2, be2) in place (fp32 + bf16)
    ln_kernel<<<Mrows, 256, 0, stream>>>(xn, g2, be2, xn, xn_bf);
    // 7. out = xn2 + b2; FFN in hidden chunks of HC
    init_out_kernel<<<(Mrows * Ee) / 256, 256, 0, stream>>>(xn, b2, out);
    for (int c0 = 0; c0 < HIDs; c0 += HC) {
        mfma_gemm<<<dim3(HC / 128, Mrows / 128), 256, 0, stream>>>(
            xn_bf, 512, w1T + (size_t)c0 * 512, 512, nullptr, h_bf, HC, 512, b1 + c0, 2);
        mfma_gemm<<<dim3(512 / 128, Mrows / 128), 256, 0, stream>>>(
            h_bf, HC, w2T + c0, HIDs, out, nullptr, 512, HC, nullptr, 3);
    }
}

// Round 4
// 604.371 us; speedup vs baseline: 10.2899x; 2.6003x over previous
//
#include <hip/hip_runtime.h>
#include <hip/hip_bf16.h>
#include <math.h>

// Problem constants (B,T,E)=(4,2048,512), H=8, D=64, HID=H*E=4096.
#define Bsz 4
#define Tt 2048
#define Ee 512
#define Hh 8
#define Dd 64
#define HIDs 4096
#define Mrows (Bsz * Tt)   // 8192 token rows
#define HC 1024            // FFN hidden chunk

typedef __attribute__((ext_vector_type(8))) short short8;   // 8 bf16 (4 VGPRs)
typedef __attribute__((ext_vector_type(4))) float f32x4;    // MFMA accumulator

__device__ __forceinline__ unsigned short f2bfu(float f) {   // RNE float->bf16 bits
    unsigned u = __float_as_uint(f);
    return (unsigned short)((u + 0x7fffu + ((u >> 16) & 1u)) >> 16);
}
__device__ __forceinline__ unsigned scale2(unsigned w, float s) {  // 2xbf16 *= s
    float lo = __uint_as_float(w << 16) * s;
    float hi = __uint_as_float(w & 0xffff0000u) * s;
    return (unsigned)f2bfu(lo) | ((unsigned)f2bfu(hi) << 16);
}

// ---------------------------------------------------------------------------
// LayerNorm: one 256-thread block per row of 512. Writes fp32 + bf16 copies.
__global__ __launch_bounds__(256) void ln_kernel(const float* __restrict__ x,
        const float* __restrict__ g, const float* __restrict__ b,
        float* __restrict__ out, __hip_bfloat16* __restrict__ out_bf) {
    int row = blockIdx.x;
    int tid = threadIdx.x;
    const float* xr = x + (size_t)row * Ee;
    float v0 = xr[tid];
    float v1 = xr[tid + 256];
    float s = v0 + v1;
    float sq = v0 * v0 + v1 * v1;
#pragma unroll
    for (int off = 32; off > 0; off >>= 1) {
        s  += __shfl_xor(s, off, 64);
        sq += __shfl_xor(sq, off, 64);
    }
    __shared__ float ls[4], lq[4];
    int wid = tid >> 6, lane = tid & 63;
    if (lane == 0) { ls[wid] = s; lq[wid] = sq; }
    __syncthreads();
    s  = ls[0] + ls[1] + ls[2] + ls[3];
    sq = lq[0] + lq[1] + lq[2] + lq[3];
    float mean = s * (1.0f / Ee);
    float var  = sq * (1.0f / Ee) - mean * mean;   // biased var, like jnp.var
    float rstd = rsqrtf(var + 1e-5f);
    float o0 = (v0 - mean) * rstd * g[tid]       + b[tid];
    float o1 = (v1 - mean) * rstd * g[tid + 256] + b[tid + 256];
    float* orow = out + (size_t)row * Ee;
    orow[tid]       = o0;
    orow[tid + 256] = o1;
    __hip_bfloat16* brow = out_bf + (size_t)row * Ee;
    brow[tid]       = __float2bfloat16(o0);
    brow[tid + 256] = __float2bfloat16(o1);
}

// ---------------------------------------------------------------------------
// Generic fp32 [R][C] -> bf16 [C][R] transpose, 64x64 LDS tiles.
__global__ __launch_bounds__(256) void transpose_bf16(const float* __restrict__ in,
        __hip_bfloat16* __restrict__ outp, int R, int C) {
    __shared__ float tile[64][65];
    int c0 = blockIdx.x * 64, r0 = blockIdx.y * 64;
    int tc = threadIdx.x & 63, tg = threadIdx.x >> 6;
#pragma unroll
    for (int i = 0; i < 16; ++i) {
        int r = tg * 16 + i;
        tile[r][tc] = in[(size_t)(r0 + r) * C + c0 + tc];
    }
    __syncthreads();
#pragma unroll
    for (int i = 0; i < 16; ++i) {
        int cc = tg * 16 + i;
        outp[(size_t)(c0 + cc) * R + r0 + tc] = __float2bfloat16(tile[tc][cc]);
    }
}

// ---------------------------------------------------------------------------
// Repack Wq/Wk/Wv [H,E,D] fp32 -> bqT [3*H*D][E] bf16 (row c=p*512+h*64+d).
__global__ __launch_bounds__(256) void repack_qkv_t(const float* __restrict__ Wq,
        const float* __restrict__ Wk, const float* __restrict__ Wv,
        __hip_bfloat16* __restrict__ bqT) {
    int blk = blockIdx.x;            // p*64 + h*8 + et
    int p = blk >> 6, h = (blk >> 3) & 7, et = blk & 7;
    const float* W = (p == 0) ? Wq : ((p == 1) ? Wk : Wv);
    __shared__ float tile[64][65];
    int td = threadIdx.x & 63, tg = threadIdx.x >> 6;
#pragma unroll
    for (int i = 0; i < 16; ++i) {
        int e = tg * 16 + i;
        tile[e][td] = W[((size_t)h * Ee + et * 64 + e) * Dd + td];
    }
    __syncthreads();
#pragma unroll
    for (int i = 0; i < 16; ++i) {
        int d = tg * 16 + i;
        bqT[((size_t)(p * 512 + h * 64 + d)) * Ee + et * 64 + td] = __float2bfloat16(tile[td][d]);
    }
}

// ---------------------------------------------------------------------------
// bf16 MFMA GEMM (m97 recipe): 128x128 tile, BK=32, global_load_lds width 16.
__global__ __launch_bounds__(256) void mfma_gemm(
        const __hip_bfloat16* __restrict__ A, int lda,
        const __hip_bfloat16* __restrict__ B, int ldb,
        float* __restrict__ Cf, __hip_bfloat16* __restrict__ Cb, int ldc, int K,
        const float* __restrict__ bias, int mode) {
    __shared__ __hip_bfloat16 As[128 * 32];   // [m][k], rows of 32 contiguous
    __shared__ __hip_bfloat16 Bs[128 * 32];   // [n][k]
    int tid = threadIdx.x;
    int lane = tid & 63, wave = tid >> 6;
    int wm = wave >> 1, wn = wave & 1;
    int row0 = blockIdx.y * 128, col0 = blockIdx.x * 128;
    f32x4 acc[4][4];
#pragma unroll
    for (int i = 0; i < 4; ++i)
#pragma unroll
        for (int j = 0; j < 4; ++j) acc[i][j] = (f32x4){0.f, 0.f, 0.f, 0.f};

    int fr = lane & 15;
    int kq = (lane >> 4) << 3;            // fragment k-offset: 0/8/16/24

    for (int k0 = 0; k0 < K; k0 += 32) {
        __syncthreads();
#pragma unroll
        for (int j = 0; j < 2; ++j) {
            int c  = j * 256 + tid;               // 16B chunk id (per-lane)
            int cb = j * 256 + wave * 64;         // wave-uniform LDS base chunk
            int r  = c >> 2, kg = (c & 3) << 3;
            __builtin_amdgcn_global_load_lds(
                (const __attribute__((address_space(1))) void*)(A + (size_t)(row0 + r) * lda + k0 + kg),
                (__attribute__((address_space(3))) void*)(As + cb * 8), 16, 0, 0);
            __builtin_amdgcn_global_load_lds(
                (const __attribute__((address_space(1))) void*)(B + (size_t)(col0 + r) * ldb + k0 + kg),
                (__attribute__((address_space(3))) void*)(Bs + cb * 8), 16, 0, 0);
        }
        __syncthreads();
        short8 afr[4], bfr[4];
#pragma unroll
        for (int i = 0; i < 4; ++i) {
            afr[i] = *(const short8*)(As + (wm * 64 + i * 16 + fr) * 32 + kq);
            bfr[i] = *(const short8*)(Bs + (wn * 64 + i * 16 + fr) * 32 + kq);
        }
#pragma unroll
        for (int i = 0; i < 4; ++i)
#pragma unroll
            for (int j = 0; j < 4; ++j)
                acc[i][j] = __builtin_amdgcn_mfma_f32_16x16x32_bf16(afr[i], bfr[j], acc[i][j], 0, 0, 0);
    }
    // epilogue: C/D layout col=lane&15, row=(lane>>4)*4+reg
    int rq = (lane >> 4) << 2;
#pragma unroll
    for (int i = 0; i < 4; ++i) {
#pragma unroll
        for (int j = 0; j < 4; ++j) {
#pragma unroll
            for (int gidx = 0; gidx < 4; ++gidx) {
                int r = row0 + wm * 64 + i * 16 + rq + gidx;
                int c = col0 + wn * 64 + j * 16 + fr;
                size_t ci = (size_t)r * ldc + c;
                float v = acc[i][j][gidx];
                if (mode == 0) {
                    Cb[ci] = __float2bfloat16(v);
                } else if (mode == 1) {
                    Cf[ci] = Cf[ci] + v + bias[c];
                } else if (mode == 2) {
                    float t = v + bias[c];
                    Cb[ci] = __float2bfloat16(t > 0.f ? t : 0.f);
                } else {
                    Cf[ci] += v;
                }
            }
        }
    }
}

// ---------------------------------------------------------------------------
// MFMA flash attention. One block = 64 Q rows of one (b,h); 4 waves x 16 rows.
// Per 64-wide S tile: QK^T via 8 MFMAs (A=Q frag, B=K[s][d] LDS tile), online
// softmax on C-layout (row-reduce = 16-lane shuffles), P -> LDS [q][s] fp32 ->
// re-read as bf16 A-frags, PV via 8 MFMAs (B=V^T[d][s] LDS tile).
// Scale (T**-0.5) folded into Q staging. Heavy q-blocks dispatched first.
__global__ __launch_bounds__(256) void attn_mfma(const __hip_bfloat16* __restrict__ qkvb,
        __hip_bfloat16* __restrict__ ob) {
    __shared__ __hip_bfloat16 KsS[64 * 72];   // K tile [s][d], pad 72
    __shared__ __hip_bfloat16 VtS[64 * 72];   // V^T tile [d][s], pad 72
    __shared__ float PsS[4 * 16 * 68];        // P [wave][q][s], pad 68; Qs overlays
    __hip_bfloat16* Qs = (__hip_bfloat16*)PsS;

    const unsigned short* q16 = (const unsigned short*)qkvb;
    int tid  = threadIdx.x;
    int lane = tid & 63, wave = tid >> 6;
    int g = lane >> 4, c = lane & 15;
    int blk = blockIdx.x;
    int bh  = blk >> 5;
    int qb  = 31 - (blk & 31);                // heavy-first
    int b = bh >> 3, h = bh & 7;
    int base = qb * 64;
    size_t tokbase = (size_t)b * Tt;
    int qoff = h * 64, koff = 512 + h * 64, voff = 1024 + h * 64;
    const float scale = 0.022097086912079608f;   // T**-0.5 per reference

    // ---- stage Q (pre-scaled) into Qs[q][72]
    {
        int q = tid >> 2, dg = (tid & 3) * 16;
        const unsigned short* src = q16 + (tokbase + base + q) * 1536 + qoff + dg;
        uint4 a  = *(const uint4*)src;
        uint4 b4 = *(const uint4*)(src + 8);
        uint4 ra, rb;
        ra.x = scale2(a.x, scale);  ra.y = scale2(a.y, scale);
        ra.z = scale2(a.z, scale);  ra.w = scale2(a.w, scale);
        rb.x = scale2(b4.x, scale); rb.y = scale2(b4.y, scale);
        rb.z = scale2(b4.z, scale); rb.w = scale2(b4.w, scale);
        *(uint4*)(Qs + q * 72 + dg)     = ra;
        *(uint4*)(Qs + q * 72 + dg + 8) = rb;
    }
    __syncthreads();
    // ---- extract this wave's Q fragments once (A: m=lane&15=q, k=quad*8+j)
    short8 aq[2];
    aq[0] = *(const short8*)(Qs + (wave * 16 + c) * 72 + g * 8);
    aq[1] = *(const short8*)(Qs + (wave * 16 + c) * 72 + 32 + g * 8);

    f32x4 acc[4];
#pragma unroll
    for (int dt = 0; dt < 4; ++dt) acc[dt] = (f32x4){0.f, 0.f, 0.f, 0.f};
    float mrow[4] = {-1e30f, -1e30f, -1e30f, -1e30f};
    float lrow[4] = {0.f, 0.f, 0.f, 0.f};
    float* Psw = PsS + wave * (16 * 68);

    for (int tile = 0; tile <= qb; ++tile) {
        int s0 = tile * 64;
        __syncthreads();                      // prior tile's LDS reads done (also Q frags)
        {   // stage K tile raw: Ks[s][d]
            int s = tid >> 2, dg = (tid & 3) * 16;
            const unsigned short* src = q16 + (tokbase + s0 + s) * 1536 + koff + dg;
            uint4 a  = *(const uint4*)src;
            uint4 b4 = *(const uint4*)(src + 8);
            *(uint4*)(KsS + s * 72 + dg)     = a;
            *(uint4*)(KsS + s * 72 + dg + 8) = b4;
        }
        {   // stage V transposed: Vt[d][s], packed u32 (s even/odd pair)
            int sp = (tid & 31) * 2, dg8 = (tid >> 5) * 8;
            const unsigned short* r0p = q16 + (tokbase + s0 + sp) * 1536 + voff + dg8;
            uint4 va = *(const uint4*)r0p;
            uint4 vb = *(const uint4*)(r0p + 1536);
            unsigned a0[4] = {va.x, va.y, va.z, va.w};
            unsigned b0[4] = {vb.x, vb.y, vb.z, vb.w};
#pragma unroll
            for (int i = 0; i < 4; ++i) {
                unsigned p0 = (a0[i] & 0xffffu) | (b0[i] << 16);
                unsigned p1 = (a0[i] >> 16) | (b0[i] & 0xffff0000u);
                *(unsigned*)(VtS + (dg8 + 2 * i) * 72 + sp)     = p0;
                *(unsigned*)(VtS + (dg8 + 2 * i + 1) * 72 + sp) = p1;
            }
        }
        __syncthreads();
        // ---- QK^T: S[16 q][64 s] per wave
        f32x4 Sc[4];
#pragma unroll
        for (int st = 0; st < 4; ++st) Sc[st] = (f32x4){0.f, 0.f, 0.f, 0.f};
#pragma unroll
        for (int ks = 0; ks < 2; ++ks)
#pragma unroll
            for (int st = 0; st < 4; ++st) {
                short8 bk = *(const short8*)(KsS + (st * 16 + c) * 72 + ks * 32 + g * 8);
                Sc[st] = __builtin_amdgcn_mfma_f32_16x16x32_bf16(aq[ks], bk, Sc[st], 0, 0, 0);
            }
        if (tile == qb) {                     // causal mask on the diagonal tile
            int qg = base + wave * 16 + g * 4;
#pragma unroll
            for (int st = 0; st < 4; ++st) {
                int sg = s0 + st * 16 + c;
#pragma unroll
                for (int r = 0; r < 4; ++r)
                    if (sg > qg + r) Sc[st][r] = -1e30f;
            }
        }
        // ---- online softmax (per q-row = per reg; 16-lane subgroup reductions)
        float pr[4][4], cc[4];
#pragma unroll
        for (int r = 0; r < 4; ++r) {
            float mv = fmaxf(fmaxf(Sc[0][r], Sc[1][r]), fmaxf(Sc[2][r], Sc[3][r]));
#pragma unroll
            for (int off = 1; off < 16; off <<= 1)
                mv = fmaxf(mv, __shfl_xor(mv, off, 64));
            float mn = fmaxf(mrow[r], mv);
            cc[r] = __expf(mrow[r] - mn);
            mrow[r] = mn;
            float s = 0.f;
#pragma unroll
            for (int st = 0; st < 4; ++st) {
                float p = __expf(Sc[st][r] - mn);
                pr[st][r] = p;
                s += p;
            }
#pragma unroll
            for (int off = 1; off < 16; off <<= 1)
                s += __shfl_xor(s, off, 64);
            lrow[r] = lrow[r] * cc[r] + s;
        }
        // ---- P -> LDS [q][s] (same-wave region; DS ops in-order, no barrier)
#pragma unroll
        for (int st = 0; st < 4; ++st)
#pragma unroll
            for (int r = 0; r < 4; ++r)
                Psw[(g * 4 + r) * 68 + st * 16 + c] = pr[st][r];
#pragma unroll
        for (int dt = 0; dt < 4; ++dt)
#pragma unroll
            for (int r = 0; r < 4; ++r)
                acc[dt][r] *= cc[r];
        // ---- PV: O[16 q][64 d] accumulate
#pragma unroll
        for (int ks = 0; ks < 2; ++ks) {
            float4 pa = *(const float4*)(Psw + c * 68 + ks * 32 + g * 8);
            float4 pb = *(const float4*)(Psw + c * 68 + ks * 32 + g * 8 + 4);
            short8 ap;
            ap[0] = (short)f2bfu(pa.x); ap[1] = (short)f2bfu(pa.y);
            ap[2] = (short)f2bfu(pa.z); ap[3] = (short)f2bfu(pa.w);
            ap[4] = (short)f2bfu(pb.x); ap[5] = (short)f2bfu(pb.y);
            ap[6] = (short)f2bfu(pb.z); ap[7] = (short)f2bfu(pb.w);
#pragma unroll
            for (int dt = 0; dt < 4; ++dt) {
                short8 bv = *(const short8*)(VtS + (dt * 16 + c) * 72 + ks * 32 + g * 8);
                acc[dt] = __builtin_amdgcn_mfma_f32_16x16x32_bf16(ap, bv, acc[dt], 0, 0, 0);
            }
        }
    }
    // ---- epilogue: O[q][d] = acc/l -> o_bf [B*T][512]
#pragma unroll
    for (int dt = 0; dt < 4; ++dt)
#pragma unroll
        for (int r = 0; r < 4; ++r) {
            int row = base + wave * 16 + g * 4 + r;
            float o = acc[dt][r] / lrow[r];
            ob[(tokbase + row) * 512 + h * 64 + dt * 16 + c] = __float2bfloat16(o);
        }
}

// ---------------------------------------------------------------------------
// out = xn2 + b2 (broadcast); FFN2 chunks then accumulate into out.
__global__ __launch_bounds__(256) void init_out_kernel(const float* __restrict__ xn2,
        const float* __restrict__ b2, float* __restrict__ out) {
    int idx = blockIdx.x * 256 + threadIdx.x;
    out[idx] = xn2[idx] + b2[idx & 511];
}

// ---------------------------------------------------------------------------
extern "C" void kernel_launch(void* const* d_in, const int* in_sizes, int n_in,
                              void* d_out, int out_size, void* d_ws, size_t ws_size,
                              hipStream_t stream) {
    const float* x   = (const float*)d_in[0];
    const float* Wq  = (const float*)d_in[1];
    const float* Wk  = (const float*)d_in[2];
    const float* Wv  = (const float*)d_in[3];
    const float* Wo  = (const float*)d_in[4];
    const float* bo  = (const float*)d_in[5];
    const float* W1  = (const float*)d_in[6];
    const float* b1  = (const float*)d_in[7];
    const float* W2  = (const float*)d_in[8];
    const float* b2  = (const float*)d_in[9];
    const float* g1  = (const float*)d_in[10];
    const float* be1 = (const float*)d_in[11];
    const float* g2  = (const float*)d_in[12];
    const float* be2 = (const float*)d_in[13];
    float* out = (float*)d_out;

    // Workspace layout (byte offsets, all 16B-aligned). Total ~86 MB.
    char* ws = (char*)d_ws;
    float*          xn     = (float*)(ws);                           // [8192][512] fp32
    __hip_bfloat16* xn_bf  = (__hip_bfloat16*)(ws + 16777216);       // [8192][512] bf16
    __hip_bfloat16* qkv_bf = (__hip_bfloat16*)(ws + 25165824);       // [8192][1536] bf16
    __hip_bfloat16* o_bf   = (__hip_bfloat16*)(ws + 50331648);       // [8192][512] bf16
    __hip_bfloat16* h_bf   = (__hip_bfloat16*)(ws + 58720256);       // [8192][HC] bf16
    __hip_bfloat16* bqT    = (__hip_bfloat16*)(ws + 75497472);       // [1536][512] bf16
    __hip_bfloat16* woT    = (__hip_bfloat16*)(ws + 77070336);       // [512][512] bf16
    __hip_bfloat16* w1T    = (__hip_bfloat16*)(ws + 77594624);       // [4096][512] bf16
    __hip_bfloat16* w2T    = (__hip_bfloat16*)(ws + 81788928);       // [512][4096] bf16

    // 1. xn = LN(x, g1, be1)  (fp32 + bf16)
    ln_kernel<<<Mrows, 256, 0, stream>>>(x, g1, be1, xn, xn_bf);
    // 2. weight repacks to bf16 [N][K]
    repack_qkv_t<<<192, 256, 0, stream>>>(Wq, Wk, Wv, bqT);
    transpose_bf16<<<dim3(8, 8),  256, 0, stream>>>(Wo, woT, 512, 512);
    transpose_bf16<<<dim3(64, 8), 256, 0, stream>>>(W1, w1T, 512, HIDs);
    transpose_bf16<<<dim3(8, 64), 256, 0, stream>>>(W2, w2T, HIDs, 512);
    // 3. qkv = xn @ Wqkv  -> bf16
    mfma_gemm<<<dim3(1536 / 128, Mrows / 128), 256, 0, stream>>>(
        xn_bf, 512, bqT, 512, nullptr, qkv_bf, 1536, 512, nullptr, 0);
    // 4. causal attention (MFMA flash) -> o_bf
    attn_mfma<<<Bsz * Hh * (Tt / 64), 256, 0, stream>>>(qkv_bf, o_bf);
    // 5. xn(=x2) = xn + o @ Wo + bo   (in-place residual add)
    mfma_gemm<<<dim3(512 / 128, Mrows / 128), 256, 0, stream>>>(
        o_bf, 512, woT, 512, xn, nullptr, 512, 512, bo, 1);
    // 6. xn(=xn2) = LN(x2, g2, be2) in place (fp32 + bf16)
    ln_kernel<<<Mrows, 256, 0, stream>>>(xn, g2, be2, xn, xn_bf);
    // 7. out = xn2 + b2; FFN in hidden chunks of HC
    init_out_kernel<<<(Mrows * Ee) / 256, 256, 0, stream>>>(xn, b2, out);
    for (int c0 = 0; c0 < HIDs; c0 += HC) {
        mfma_gemm<<<dim3(HC / 128, Mrows / 128), 256, 0, stream>>>(
            xn_bf, 512, w1T + (size_t)c0 * 512, 512, nullptr, h_bf, HC, 512, b1 + c0, 2);
        mfma_gemm<<<dim3(512 / 128, Mrows / 128), 256, 0, stream>>>(
            h_bf, HC, w2T + c0, HIDs, out, nullptr, 512, HC, nullptr, 3);
    }
}

// Round 5
// 457.786 us; speedup vs baseline: 13.5848x; 1.3202x over previous
//
#include <hip/hip_runtime.h>
#include <hip/hip_bf16.h>
#include <math.h>

// Problem constants (B,T,E)=(4,2048,512), H=8, D=64, HID=H*E=4096.
#define Bsz 4
#define Tt 2048
#define Ee 512
#define Hh 8
#define Dd 64
#define HIDs 4096
#define Mrows (Bsz * Tt)   // 8192 token rows

typedef __attribute__((ext_vector_type(8))) short short8;   // 8 bf16 (4 VGPRs)
typedef __attribute__((ext_vector_type(4))) float f32x4;    // MFMA accumulator

__device__ __forceinline__ unsigned short f2bfu(float f) {   // RNE float->bf16 bits
    unsigned u = __float_as_uint(f);
    return (unsigned short)((u + 0x7fffu + ((u >> 16) & 1u)) >> 16);
}
__device__ __forceinline__ unsigned scale2(unsigned w, float s) {  // 2xbf16 *= s
    float lo = __uint_as_float(w << 16) * s;
    float hi = __uint_as_float(w & 0xffff0000u) * s;
    return (unsigned)f2bfu(lo) | ((unsigned)f2bfu(hi) << 16);
}

// ---------------------------------------------------------------------------
// LayerNorm: one 256-thread block per row of 512.
// out_f = LN(x)*g+b + addb[col]  (fp32; addb folds the NEXT stage's bias)
// out_bf = LN(x)*g+b             (bf16 GEMM operand, no addb)
__global__ __launch_bounds__(256) void ln_kernel(const float* __restrict__ x,
        const float* __restrict__ g, const float* __restrict__ b,
        const float* __restrict__ addb,
        float* __restrict__ out_f, __hip_bfloat16* __restrict__ out_bf) {
    int row = blockIdx.x;
    int tid = threadIdx.x;
    const float* xr = x + (size_t)row * Ee;
    float v0 = xr[tid];
    float v1 = xr[tid + 256];
    float s = v0 + v1;
    float sq = v0 * v0 + v1 * v1;
#pragma unroll
    for (int off = 32; off > 0; off >>= 1) {
        s  += __shfl_xor(s, off, 64);
        sq += __shfl_xor(sq, off, 64);
    }
    __shared__ float ls[4], lq[4];
    int wid = tid >> 6, lane = tid & 63;
    if (lane == 0) { ls[wid] = s; lq[wid] = sq; }
    __syncthreads();
    s  = ls[0] + ls[1] + ls[2] + ls[3];
    sq = lq[0] + lq[1] + lq[2] + lq[3];
    float mean = s * (1.0f / Ee);
    float var  = sq * (1.0f / Ee) - mean * mean;   // biased var, like jnp.var
    float rstd = rsqrtf(var + 1e-5f);
    float o0 = (v0 - mean) * rstd * g[tid]       + b[tid];
    float o1 = (v1 - mean) * rstd * g[tid + 256] + b[tid + 256];
    float* orow = out_f + (size_t)row * Ee;
    orow[tid]       = o0 + addb[tid];
    orow[tid + 256] = o1 + addb[tid + 256];
    __hip_bfloat16* brow = out_bf + (size_t)row * Ee;
    brow[tid]       = __float2bfloat16(o0);
    brow[tid + 256] = __float2bfloat16(o1);
}

// ---------------------------------------------------------------------------
// Generic fp32 [R][C] -> bf16 [C][R] transpose, 64x64 LDS tiles.
__global__ __launch_bounds__(256) void transpose_bf16(const float* __restrict__ in,
        __hip_bfloat16* __restrict__ outp, int R, int C) {
    __shared__ float tile[64][65];
    int c0 = blockIdx.x * 64, r0 = blockIdx.y * 64;
    int tc = threadIdx.x & 63, tg = threadIdx.x >> 6;
#pragma unroll
    for (int i = 0; i < 16; ++i) {
        int r = tg * 16 + i;
        tile[r][tc] = in[(size_t)(r0 + r) * C + c0 + tc];
    }
    __syncthreads();
#pragma unroll
    for (int i = 0; i < 16; ++i) {
        int cc = tg * 16 + i;
        outp[(size_t)(c0 + cc) * R + r0 + tc] = __float2bfloat16(tile[tc][cc]);
    }
}

// ---------------------------------------------------------------------------
// Repack Wq/Wk/Wv [H,E,D] fp32 -> bqT [3*H*D][E] bf16 (row c=p*512+h*64+d).
__global__ __launch_bounds__(256) void repack_qkv_t(const float* __restrict__ Wq,
        const float* __restrict__ Wk, const float* __restrict__ Wv,
        __hip_bfloat16* __restrict__ bqT) {
    int blk = blockIdx.x;            // p*64 + h*8 + et
    int p = blk >> 6, h = (blk >> 3) & 7, et = blk & 7;
    const float* W = (p == 0) ? Wq : ((p == 1) ? Wk : Wv);
    __shared__ float tile[64][65];
    int td = threadIdx.x & 63, tg = threadIdx.x >> 6;
#pragma unroll
    for (int i = 0; i < 16; ++i) {
        int e = tg * 16 + i;
        tile[e][td] = W[((size_t)h * Ee + et * 64 + e) * Dd + td];
    }
    __syncthreads();
#pragma unroll
    for (int i = 0; i < 16; ++i) {
        int d = tg * 16 + i;
        bqT[((size_t)(p * 512 + h * 64 + d)) * Ee + et * 64 + td] = __float2bfloat16(tile[td][d]);
    }
}

// ---------------------------------------------------------------------------
// bf16 MFMA GEMM (m97 recipe): 128x128 tile, BK=32, global_load_lds width 16.
// Split-K via blockIdx.z: this block covers k in [z*Kc, (z+1)*Kc).
// Modes: 0: Cb = bf16(acc)
//        2: Cb = bf16(relu(acc + bias[c]))
//        4: atomicAdd(Cf[ci], acc)        (split-K accumulate into fp32 base)
__global__ __launch_bounds__(256) void mfma_gemm(
        const __hip_bfloat16* __restrict__ A, int lda,
        const __hip_bfloat16* __restrict__ B, int ldb,
        float* __restrict__ Cf, __hip_bfloat16* __restrict__ Cb, int ldc, int Kc,
        const float* __restrict__ bias, int mode) {
    __shared__ __hip_bfloat16 As[128 * 32];   // [m][k], rows of 32 contiguous
    __shared__ __hip_bfloat16 Bs[128 * 32];   // [n][k]
    int tid = threadIdx.x;
    int lane = tid & 63, wave = tid >> 6;
    int wm = wave >> 1, wn = wave & 1;
    int row0 = blockIdx.y * 128, col0 = blockIdx.x * 128;
    int kbase = blockIdx.z * Kc;
    f32x4 acc[4][4];
#pragma unroll
    for (int i = 0; i < 4; ++i)
#pragma unroll
        for (int j = 0; j < 4; ++j) acc[i][j] = (f32x4){0.f, 0.f, 0.f, 0.f};

    int fr = lane & 15;
    int kq = (lane >> 4) << 3;            // fragment k-offset: 0/8/16/24

    for (int k0 = kbase; k0 < kbase + Kc; k0 += 32) {
        __syncthreads();
#pragma unroll
        for (int j = 0; j < 2; ++j) {
            int c  = j * 256 + tid;               // 16B chunk id (per-lane)
            int cb = j * 256 + wave * 64;         // wave-uniform LDS base chunk
            int r  = c >> 2, kg = (c & 3) << 3;
            __builtin_amdgcn_global_load_lds(
                (const __attribute__((address_space(1))) void*)(A + (size_t)(row0 + r) * lda + k0 + kg),
                (__attribute__((address_space(3))) void*)(As + cb * 8), 16, 0, 0);
            __builtin_amdgcn_global_load_lds(
                (const __attribute__((address_space(1))) void*)(B + (size_t)(col0 + r) * ldb + k0 + kg),
                (__attribute__((address_space(3))) void*)(Bs + cb * 8), 16, 0, 0);
        }
        __syncthreads();
        short8 afr[4], bfr[4];
#pragma unroll
        for (int i = 0; i < 4; ++i) {
            afr[i] = *(const short8*)(As + (wm * 64 + i * 16 + fr) * 32 + kq);
            bfr[i] = *(const short8*)(Bs + (wn * 64 + i * 16 + fr) * 32 + kq);
        }
#pragma unroll
        for (int i = 0; i < 4; ++i)
#pragma unroll
            for (int j = 0; j < 4; ++j)
                acc[i][j] = __builtin_amdgcn_mfma_f32_16x16x32_bf16(afr[i], bfr[j], acc[i][j], 0, 0, 0);
    }
    // epilogue: C/D layout col=lane&15, row=(lane>>4)*4+reg
    int rq = (lane >> 4) << 2;
#pragma unroll
    for (int i = 0; i < 4; ++i) {
#pragma unroll
        for (int j = 0; j < 4; ++j) {
#pragma unroll
            for (int gidx = 0; gidx < 4; ++gidx) {
                int r = row0 + wm * 64 + i * 16 + rq + gidx;
                int c = col0 + wn * 64 + j * 16 + fr;
                size_t ci = (size_t)r * ldc + c;
                float v = acc[i][j][gidx];
                if (mode == 0) {
                    Cb[ci] = __float2bfloat16(v);
                } else if (mode == 2) {
                    float t = v + bias[c];
                    Cb[ci] = __float2bfloat16(t > 0.f ? t : 0.f);
                } else {
                    atomicAdd(Cf + ci, v);
                }
            }
        }
    }
}

// ---------------------------------------------------------------------------
// MFMA flash attention. One block = 64 Q rows of one (b,h); 4 waves x 16 rows.
// Per 64-wide S tile: QK^T via 8 MFMAs (A=Q frag, B=K[s][d] LDS tile), online
// softmax in base-2 domain (scale*log2e folded into Q), P -> LDS as bf16
// [q][s] -> re-read as A-frags, PV via 8 MFMAs (B=V^T[d][s] LDS tile).
// Global heavy-first block order for tail packing.
__global__ __launch_bounds__(256) void attn_mfma(const __hip_bfloat16* __restrict__ qkvb,
        __hip_bfloat16* __restrict__ ob) {
    __shared__ __hip_bfloat16 KsS[64 * 72];   // K tile [s][d], pad 72
    __shared__ __hip_bfloat16 VtS[64 * 72];   // V^T tile [d][s], pad 72
    __shared__ __hip_bfloat16 PsS[4 * 16 * 72]; // P [wave][q][s] bf16; Qs overlays
    __hip_bfloat16* Qs = PsS;

    const unsigned short* q16 = (const unsigned short*)qkvb;
    int tid  = threadIdx.x;
    int lane = tid & 63, wave = tid >> 6;
    int g = lane >> 4, c = lane & 15;
    int blk = blockIdx.x;
    int qb  = 31 - (blk >> 5);                // global heavy-first
    int bh  = blk & 31;
    int b = bh >> 3, h = bh & 7;
    int base = qb * 64;
    size_t tokbase = (size_t)b * Tt;
    int qoff = h * 64, koff = 512 + h * 64, voff = 1024 + h * 64;
    // T**-0.5 * log2(e): softmax computed with exp2
    const float qscale = 0.022097086912079608f * 1.4426950408889634f;

    // ---- stage Q (pre-scaled) into Qs[q][72]
    {
        int q = tid >> 2, dg = (tid & 3) * 16;
        const unsigned short* src = q16 + (tokbase + base + q) * 1536 + qoff + dg;
        uint4 a  = *(const uint4*)src;
        uint4 b4 = *(const uint4*)(src + 8);
        uint4 ra, rb;
        ra.x = scale2(a.x, qscale);  ra.y = scale2(a.y, qscale);
        ra.z = scale2(a.z, qscale);  ra.w = scale2(a.w, qscale);
        rb.x = scale2(b4.x, qscale); rb.y = scale2(b4.y, qscale);
        rb.z = scale2(b4.z, qscale); rb.w = scale2(b4.w, qscale);
        *(uint4*)(Qs + q * 72 + dg)     = ra;
        *(uint4*)(Qs + q * 72 + dg + 8) = rb;
    }
    __syncthreads();
    // ---- extract this wave's Q fragments once (A: m=lane&15=q, k=quad*8+j)
    short8 aq[2];
    aq[0] = *(const short8*)(Qs + (wave * 16 + c) * 72 + g * 8);
    aq[1] = *(const short8*)(Qs + (wave * 16 + c) * 72 + 32 + g * 8);

    f32x4 acc[4];
#pragma unroll
    for (int dt = 0; dt < 4; ++dt) acc[dt] = (f32x4){0.f, 0.f, 0.f, 0.f};
    float mrow[4] = {-1e30f, -1e30f, -1e30f, -1e30f};
    float lrow[4] = {0.f, 0.f, 0.f, 0.f};
    __hip_bfloat16* Psw = PsS + wave * (16 * 72);
    unsigned short* Psw16 = (unsigned short*)Psw;

    for (int tile = 0; tile <= qb; ++tile) {
        int s0 = tile * 64;
        __syncthreads();                      // prior tile's LDS reads done (also Q frags)
        {   // stage K tile raw: Ks[s][d]
            int s = tid >> 2, dg = (tid & 3) * 16;
            const unsigned short* src = q16 + (tokbase + s0 + s) * 1536 + koff + dg;
            uint4 a  = *(const uint4*)src;
            uint4 b4 = *(const uint4*)(src + 8);
            *(uint4*)(KsS + s * 72 + dg)     = a;
            *(uint4*)(KsS + s * 72 + dg + 8) = b4;
        }
        {   // stage V transposed: Vt[d][s], packed u32 (s even/odd pair)
            int sp = (tid & 31) * 2, dg8 = (tid >> 5) * 8;
            const unsigned short* r0p = q16 + (tokbase + s0 + sp) * 1536 + voff + dg8;
            uint4 va = *(const uint4*)r0p;
            uint4 vb = *(const uint4*)(r0p + 1536);
            unsigned a0[4] = {va.x, va.y, va.z, va.w};
            unsigned b0[4] = {vb.x, vb.y, vb.z, vb.w};
#pragma unroll
            for (int i = 0; i < 4; ++i) {
                unsigned p0 = (a0[i] & 0xffffu) | (b0[i] << 16);
                unsigned p1 = (a0[i] >> 16) | (b0[i] & 0xffff0000u);
                *(unsigned*)(VtS + (dg8 + 2 * i) * 72 + sp)     = p0;
                *(unsigned*)(VtS + (dg8 + 2 * i + 1) * 72 + sp) = p1;
            }
        }
        __syncthreads();
        // ---- QK^T: S[16 q][64 s] per wave (base-2 scaled scores)
        f32x4 Sc[4];
#pragma unroll
        for (int st = 0; st < 4; ++st) Sc[st] = (f32x4){0.f, 0.f, 0.f, 0.f};
#pragma unroll
        for (int ks = 0; ks < 2; ++ks)
#pragma unroll
            for (int st = 0; st < 4; ++st) {
                short8 bk = *(const short8*)(KsS + (st * 16 + c) * 72 + ks * 32 + g * 8);
                Sc[st] = __builtin_amdgcn_mfma_f32_16x16x32_bf16(aq[ks], bk, Sc[st], 0, 0, 0);
            }
        if (tile == qb) {                     // causal mask on the diagonal tile
            int qg = base + wave * 16 + g * 4;
#pragma unroll
            for (int st = 0; st < 4; ++st) {
                int sg = s0 + st * 16 + c;
#pragma unroll
                for (int r = 0; r < 4; ++r)
                    if (sg > qg + r) Sc[st][r] = -1e30f;
            }
        }
        // ---- online softmax (per q-row = per reg; 16-lane subgroup reductions)
        float pr[4][4], cc[4];
#pragma unroll
        for (int r = 0; r < 4; ++r) {
            float mv = fmaxf(fmaxf(Sc[0][r], Sc[1][r]), fmaxf(Sc[2][r], Sc[3][r]));
#pragma unroll
            for (int off = 1; off < 16; off <<= 1)
                mv = fmaxf(mv, __shfl_xor(mv, off, 64));
            float mn = fmaxf(mrow[r], mv);
            cc[r] = exp2f(mrow[r] - mn);
            mrow[r] = mn;
            float s = 0.f;
#pragma unroll
            for (int st = 0; st < 4; ++st) {
                float p = exp2f(Sc[st][r] - mn);
                pr[st][r] = p;
                s += p;
            }
#pragma unroll
            for (int off = 1; off < 16; off <<= 1)
                s += __shfl_xor(s, off, 64);
            lrow[r] = lrow[r] * cc[r] + s;
        }
        // ---- P -> LDS bf16 [q][s] (same-wave region; DS in-order, no barrier)
#pragma unroll
        for (int st = 0; st < 4; ++st)
#pragma unroll
            for (int r = 0; r < 4; ++r)
                Psw16[(g * 4 + r) * 72 + st * 16 + c] = f2bfu(pr[st][r]);
#pragma unroll
        for (int dt = 0; dt < 4; ++dt)
#pragma unroll
            for (int r = 0; r < 4; ++r)
                acc[dt][r] *= cc[r];
        // ---- PV: O[16 q][64 d] accumulate
#pragma unroll
        for (int ks = 0; ks < 2; ++ks) {
            short8 ap = *(const short8*)(Psw + c * 72 + ks * 32 + g * 8);
#pragma unroll
            for (int dt = 0; dt < 4; ++dt) {
                short8 bv = *(const short8*)(VtS + (dt * 16 + c) * 72 + ks * 32 + g * 8);
                acc[dt] = __builtin_amdgcn_mfma_f32_16x16x32_bf16(ap, bv, acc[dt], 0, 0, 0);
            }
        }
    }
    // ---- epilogue: O[q][d] = acc/l -> o_bf [B*T][512]
    float rl[4];
#pragma unroll
    for (int r = 0; r < 4; ++r) rl[r] = 1.0f / lrow[r];
#pragma unroll
    for (int dt = 0; dt < 4; ++dt)
#pragma unroll
        for (int r = 0; r < 4; ++r) {
            int row = base + wave * 16 + g * 4 + r;
            float o = acc[dt][r] * rl[r];
            ob[(tokbase + row) * 512 + h * 64 + dt * 16 + c] = __float2bfloat16(o);
        }
}

// ---------------------------------------------------------------------------
extern "C" void kernel_launch(void* const* d_in, const int* in_sizes, int n_in,
                              void* d_out, int out_size, void* d_ws, size_t ws_size,
                              hipStream_t stream) {
    const float* x   = (const float*)d_in[0];
    const float* Wq  = (const float*)d_in[1];
    const float* Wk  = (const float*)d_in[2];
    const float* Wv  = (const float*)d_in[3];
    const float* Wo  = (const float*)d_in[4];
    const float* bo  = (const float*)d_in[5];
    const float* W1  = (const float*)d_in[6];
    const float* b1  = (const float*)d_in[7];
    const float* W2  = (const float*)d_in[8];
    const float* b2  = (const float*)d_in[9];
    const float* g1  = (const float*)d_in[10];
    const float* be1 = (const float*)d_in[11];
    const float* g2  = (const float*)d_in[12];
    const float* be2 = (const float*)d_in[13];
    float* out = (float*)d_out;

    // Workspace layout (byte offsets, 16B aligned). Peak use ~98 MB.
    char* ws = (char*)d_ws;
    __hip_bfloat16* bqT    = (__hip_bfloat16*)(ws);                  // [1536][512]
    __hip_bfloat16* woT    = (__hip_bfloat16*)(ws + 1572864);        // [512][512]
    __hip_bfloat16* w1T    = (__hip_bfloat16*)(ws + 2097152);        // [4096][512]
    __hip_bfloat16* w2T    = (__hip_bfloat16*)(ws + 6291456);        // [512][4096]
    float*          xn     = (float*)(ws + 10485760);                // [8192][512] fp32 (LN1+bo; then x2; then read by LN2)
    __hip_bfloat16* xn_bf  = (__hip_bfloat16*)(ws + 27262976);       // [8192][512] bf16 (LN1 out; later LN2 out)
    __hip_bfloat16* qkv_bf = (__hip_bfloat16*)(ws + 35651584);       // [8192][1536] bf16
    __hip_bfloat16* o_bf   = (__hip_bfloat16*)(ws + 60817408);       // [8192][512] bf16
    __hip_bfloat16* h_bf   = (__hip_bfloat16*)(ws + 35651584);       // [8192][4096] overlay (qkv/o dead by FFN1)

    // 1. LN1: xn = LN(x)+bo (fp32 residual base), xn_bf = LN(x) (bf16)
    ln_kernel<<<Mrows, 256, 0, stream>>>(x, g1, be1, bo, xn, xn_bf);
    // 2. weight repacks to bf16 [N][K]
    repack_qkv_t<<<192, 256, 0, stream>>>(Wq, Wk, Wv, bqT);
    transpose_bf16<<<dim3(8, 8),  256, 0, stream>>>(Wo, woT, 512, 512);
    transpose_bf16<<<dim3(64, 8), 256, 0, stream>>>(W1, w1T, 512, HIDs);
    transpose_bf16<<<dim3(8, 64), 256, 0, stream>>>(W2, w2T, HIDs, 512);
    // 3. qkv = xn @ Wqkv  -> bf16
    mfma_gemm<<<dim3(12, 64, 1), 256, 0, stream>>>(
        xn_bf, 512, bqT, 512, nullptr, qkv_bf, 1536, 512, nullptr, 0);
    // 4. causal attention (MFMA flash) -> o_bf
    attn_mfma<<<Bsz * Hh * (Tt / 64), 256, 0, stream>>>(qkv_bf, o_bf);
    // 5. xn(=x2) += o @ Wo   (split-K=2, atomic fp32 accumulate)
    mfma_gemm<<<dim3(4, 64, 2), 256, 0, stream>>>(
        o_bf, 512, woT, 512, xn, nullptr, 512, 256, nullptr, 4);
    // 6. LN2: out = LN(x2)+b2 (fp32, final residual base), xn_bf = LN(x2)
    ln_kernel<<<Mrows, 256, 0, stream>>>(xn, g2, be2, b2, out, xn_bf);
    // 7. h = relu(xn2 @ W1 + b1)  (single N=4096 GEMM)
    mfma_gemm<<<dim3(32, 64, 1), 256, 0, stream>>>(
        xn_bf, 512, w1T, 512, nullptr, h_bf, HIDs, 512, b1, 2);
    // 8. out += h @ W2  (split-K=4, atomic fp32 accumulate)
    mfma_gemm<<<dim3(4, 64, 4), 256, 0, stream>>>(
        h_bf, HIDs, w2T, HIDs, out, nullptr, 512, 1024, nullptr, 4);
}

// Round 6
// 451.031 us; speedup vs baseline: 13.7883x; 1.0150x over previous
//
#include <hip/hip_runtime.h>
#include <hip/hip_bf16.h>
#include <math.h>

// Problem constants (B,T,E)=(4,2048,512), H=8, D=64, HID=H*E=4096.
#define Bsz 4
#define Tt 2048
#define Ee 512
#define Hh 8
#define Dd 64
#define HIDs 4096
#define Mrows (Bsz * Tt)   // 8192 token rows

typedef __attribute__((ext_vector_type(8))) short short8;   // 8 bf16 (4 VGPRs)
typedef __attribute__((ext_vector_type(4))) float f32x4;    // MFMA accumulator

__device__ __forceinline__ unsigned short f2bfu(float f) {   // RNE float->bf16 bits
    unsigned u = __float_as_uint(f);
    return (unsigned short)((u + 0x7fffu + ((u >> 16) & 1u)) >> 16);
}
__device__ __forceinline__ unsigned scale2(unsigned w, float s) {  // 2xbf16 *= s
    float lo = __uint_as_float(w << 16) * s;
    float hi = __uint_as_float(w & 0xffff0000u) * s;
    return (unsigned)f2bfu(lo) | ((unsigned)f2bfu(hi) << 16);
}

// ---------------------------------------------------------------------------
// LayerNorm: one 256-thread block per row of 512.
// out_f = LN(x)*g+b + addb[col]  (fp32; addb folds the NEXT stage's bias)
// out_bf = LN(x)*g+b             (bf16 GEMM operand, no addb)
__global__ __launch_bounds__(256) void ln_kernel(const float* __restrict__ x,
        const float* __restrict__ g, const float* __restrict__ b,
        const float* __restrict__ addb,
        float* __restrict__ out_f, __hip_bfloat16* __restrict__ out_bf) {
    int row = blockIdx.x;
    int tid = threadIdx.x;
    const float* xr = x + (size_t)row * Ee;
    float v0 = xr[tid];
    float v1 = xr[tid + 256];
    float s = v0 + v1;
    float sq = v0 * v0 + v1 * v1;
#pragma unroll
    for (int off = 32; off > 0; off >>= 1) {
        s  += __shfl_xor(s, off, 64);
        sq += __shfl_xor(sq, off, 64);
    }
    __shared__ float ls[4], lq[4];
    int wid = tid >> 6, lane = tid & 63;
    if (lane == 0) { ls[wid] = s; lq[wid] = sq; }
    __syncthreads();
    s  = ls[0] + ls[1] + ls[2] + ls[3];
    sq = lq[0] + lq[1] + lq[2] + lq[3];
    float mean = s * (1.0f / Ee);
    float var  = sq * (1.0f / Ee) - mean * mean;   // biased var, like jnp.var
    float rstd = rsqrtf(var + 1e-5f);
    float o0 = (v0 - mean) * rstd * g[tid]       + b[tid];
    float o1 = (v1 - mean) * rstd * g[tid + 256] + b[tid + 256];
    float* orow = out_f + (size_t)row * Ee;
    orow[tid]       = o0 + addb[tid];
    orow[tid + 256] = o1 + addb[tid + 256];
    __hip_bfloat16* brow = out_bf + (size_t)row * Ee;
    brow[tid]       = __float2bfloat16(o0);
    brow[tid + 256] = __float2bfloat16(o1);
}

// ---------------------------------------------------------------------------
// Generic fp32 [R][C] -> bf16 [C][R] transpose, 64x64 LDS tiles.
__global__ __launch_bounds__(256) void transpose_bf16(const float* __restrict__ in,
        __hip_bfloat16* __restrict__ outp, int R, int C) {
    __shared__ float tile[64][65];
    int c0 = blockIdx.x * 64, r0 = blockIdx.y * 64;
    int tc = threadIdx.x & 63, tg = threadIdx.x >> 6;
#pragma unroll
    for (int i = 0; i < 16; ++i) {
        int r = tg * 16 + i;
        tile[r][tc] = in[(size_t)(r0 + r) * C + c0 + tc];
    }
    __syncthreads();
#pragma unroll
    for (int i = 0; i < 16; ++i) {
        int cc = tg * 16 + i;
        outp[(size_t)(c0 + cc) * R + r0 + tc] = __float2bfloat16(tile[tc][cc]);
    }
}

// ---------------------------------------------------------------------------
// Repack Wq/Wk/Wv [H,E,D] fp32 -> bqT [3*H*D][E] bf16 (row c=p*512+h*64+d).
__global__ __launch_bounds__(256) void repack_qkv_t(const float* __restrict__ Wq,
        const float* __restrict__ Wk, const float* __restrict__ Wv,
        __hip_bfloat16* __restrict__ bqT) {
    int blk = blockIdx.x;            // p*64 + h*8 + et
    int p = blk >> 6, h = (blk >> 3) & 7, et = blk & 7;
    const float* W = (p == 0) ? Wq : ((p == 1) ? Wk : Wv);
    __shared__ float tile[64][65];
    int td = threadIdx.x & 63, tg = threadIdx.x >> 6;
#pragma unroll
    for (int i = 0; i < 16; ++i) {
        int e = tg * 16 + i;
        tile[e][td] = W[((size_t)h * Ee + et * 64 + e) * Dd + td];
    }
    __syncthreads();
#pragma unroll
    for (int i = 0; i < 16; ++i) {
        int d = tg * 16 + i;
        bqT[((size_t)(p * 512 + h * 64 + d)) * Ee + et * 64 + td] = __float2bfloat16(tile[td][d]);
    }
}

// ---------------------------------------------------------------------------
// bf16 MFMA GEMM: 128x128 tile, BK=64 as two 32-wide k-panels (each panel
// keeps the 64B-row LDS layout -> only 2-way bank aliasing on ds_read_b128),
// global_load_lds width 16. 1D grid with XCD-aware swizzle: slots L%8 (one
// XCD, per round-robin heuristic) map to contiguous virtual ids -> same A
// row-tiles stay in one XCD's L2. Split-K via virtual z.
// Modes: 0: Cb = bf16(acc)
//        2: Cb = bf16(relu(acc + bias[c]))
//        4: atomicAdd(Cf[ci], acc)        (split-K accumulate into fp32 base)
__global__ __launch_bounds__(256) void mfma_gemm(
        const __hip_bfloat16* __restrict__ A, int lda,
        const __hip_bfloat16* __restrict__ B, int ldb,
        float* __restrict__ Cf, __hip_bfloat16* __restrict__ Cb, int ldc, int Kc,
        const float* __restrict__ bias, int mode, int nx, int ny) {
    __shared__ __hip_bfloat16 As[2 * 128 * 32];   // [panel][m][k32]
    __shared__ __hip_bfloat16 Bs[2 * 128 * 32];   // [panel][n][k32]
    int tid = threadIdx.x;
    int lane = tid & 63, wave = tid >> 6;
    int wm = wave >> 1, wn = wave & 1;
    // XCD swizzle: v = (L%8)*slots + L/8
    int L = blockIdx.x;
    int slots = (int)gridDim.x >> 3;
    int v = (L & 7) * slots + (L >> 3);
    int bx = v % nx;
    int rem = v / nx;
    int by = rem % ny;
    int bz = rem / ny;
    int row0 = by * 128, col0 = bx * 128;
    int kbase = bz * Kc;
    f32x4 acc[4][4];
#pragma unroll
    for (int i = 0; i < 4; ++i)
#pragma unroll
        for (int j = 0; j < 4; ++j) acc[i][j] = (f32x4){0.f, 0.f, 0.f, 0.f};

    int fr = lane & 15;
    int kq = (lane >> 4) << 3;            // fragment k-offset: 0/8/16/24

    for (int k0 = kbase; k0 < kbase + Kc; k0 += 64) {
        __syncthreads();
        // stage 2 k-panels per matrix: chunk c in [0,1024): panel=c>>9,
        // r=(c&511)>>2, kg=(c&3)<<3. LDS dst = chunk-contiguous (c*8).
#pragma unroll
        for (int j = 0; j < 4; ++j) {
            int c  = j * 256 + tid;
            int cb = j * 256 + wave * 64;         // wave-uniform base chunk
            int p  = c >> 9, cp = c & 511;
            int r  = cp >> 2, kg = (cp & 3) << 3;
            int ko = k0 + p * 32 + kg;
            __builtin_amdgcn_global_load_lds(
                (const __attribute__((address_space(1))) void*)(A + (size_t)(row0 + r) * lda + ko),
                (__attribute__((address_space(3))) void*)(As + cb * 8), 16, 0, 0);
            __builtin_amdgcn_global_load_lds(
                (const __attribute__((address_space(1))) void*)(B + (size_t)(col0 + r) * ldb + ko),
                (__attribute__((address_space(3))) void*)(Bs + cb * 8), 16, 0, 0);
        }
        __syncthreads();
#pragma unroll
        for (int ks = 0; ks < 2; ++ks) {
            short8 afr[4], bfr[4];
#pragma unroll
            for (int i = 0; i < 4; ++i) {
                afr[i] = *(const short8*)(As + ks * 4096 + (wm * 64 + i * 16 + fr) * 32 + kq);
                bfr[i] = *(const short8*)(Bs + ks * 4096 + (wn * 64 + i * 16 + fr) * 32 + kq);
            }
#pragma unroll
            for (int i = 0; i < 4; ++i)
#pragma unroll
                for (int j = 0; j < 4; ++j)
                    acc[i][j] = __builtin_amdgcn_mfma_f32_16x16x32_bf16(afr[i], bfr[j], acc[i][j], 0, 0, 0);
        }
    }
    // epilogue: C/D layout col=lane&15, row=(lane>>4)*4+reg
    int rq = (lane >> 4) << 2;
#pragma unroll
    for (int i = 0; i < 4; ++i) {
#pragma unroll
        for (int j = 0; j < 4; ++j) {
#pragma unroll
            for (int gidx = 0; gidx < 4; ++gidx) {
                int r = row0 + wm * 64 + i * 16 + rq + gidx;
                int c = col0 + wn * 64 + j * 16 + fr;
                size_t ci = (size_t)r * ldc + c;
                float val = acc[i][j][gidx];
                if (mode == 0) {
                    Cb[ci] = __float2bfloat16(val);
                } else if (mode == 2) {
                    float t = val + bias[c];
                    Cb[ci] = __float2bfloat16(t > 0.f ? t : 0.f);
                } else {
                    atomicAdd(Cf + ci, val);
                }
            }
        }
    }
}

// ---------------------------------------------------------------------------
// MFMA flash attention. One block = 128 Q rows of one (b,h); 8 waves x 16
// rows. Per 64-wide S tile: QK^T via 8 MFMAs (A=Q frag, B=K[s][d] LDS tile),
// online softmax in base-2 domain (scale*log2e folded into Q), P -> LDS bf16
// [q][s] -> A-frags, PV via 8 MFMAs (B=V^T[d][s] LDS tile). Waves 0-3 skip
// compute on the final tile (fully masked for them). Heavy blocks first.
__global__ __launch_bounds__(512) void attn_mfma(const __hip_bfloat16* __restrict__ qkvb,
        __hip_bfloat16* __restrict__ ob) {
    __shared__ __hip_bfloat16 KsS[64 * 72];     // K tile [s][d], pad 72
    __shared__ __hip_bfloat16 VtS[64 * 72];     // V^T tile [d][s], pad 72
    __shared__ __hip_bfloat16 PsS[8 * 16 * 72]; // P [wave][q][s] bf16; Q overlays
    __hip_bfloat16* Qs = PsS;                   // Q staging [128 q][72]

    const unsigned short* q16 = (const unsigned short*)qkvb;
    int tid  = threadIdx.x;
    int lane = tid & 63, wave = tid >> 6;
    int g = lane >> 4, c = lane & 15;
    int blk = blockIdx.x;
    int qb  = 15 - (blk >> 5);                // global heavy-first
    int bh  = blk & 31;
    int b = bh >> 3, h = bh & 7;
    int base = qb * 128;
    size_t tokbase = (size_t)b * Tt;
    int qoff = h * 64, koff = 512 + h * 64, voff = 1024 + h * 64;
    // T**-0.5 * log2(e): softmax computed with exp2
    const float qscale = 0.022097086912079608f * 1.4426950408889634f;

    // ---- stage Q (pre-scaled) into Qs[q][72], 128 rows
    {
        int q = tid >> 2, dg = (tid & 3) * 16;
        const unsigned short* src = q16 + (tokbase + base + q) * 1536 + qoff + dg;
        uint4 a  = *(const uint4*)src;
        uint4 b4 = *(const uint4*)(src + 8);
        uint4 ra, rb;
        ra.x = scale2(a.x, qscale);  ra.y = scale2(a.y, qscale);
        ra.z = scale2(a.z, qscale);  ra.w = scale2(a.w, qscale);
        rb.x = scale2(b4.x, qscale); rb.y = scale2(b4.y, qscale);
        rb.z = scale2(b4.z, qscale); rb.w = scale2(b4.w, qscale);
        *(uint4*)(Qs + q * 72 + dg)     = ra;
        *(uint4*)(Qs + q * 72 + dg + 8) = rb;
    }
    __syncthreads();
    // ---- extract this wave's Q fragments once (A: m=lane&15=q, k=quad*8+j)
    short8 aq[2];
    aq[0] = *(const short8*)(Qs + (wave * 16 + c) * 72 + g * 8);
    aq[1] = *(const short8*)(Qs + (wave * 16 + c) * 72 + 32 + g * 8);

    f32x4 acc[4];
#pragma unroll
    for (int dt = 0; dt < 4; ++dt) acc[dt] = (f32x4){0.f, 0.f, 0.f, 0.f};
    float mrow[4] = {-1e30f, -1e30f, -1e30f, -1e30f};
    float lrow[4] = {0.f, 0.f, 0.f, 0.f};
    __hip_bfloat16* Psw = PsS + wave * (16 * 72);
    unsigned short* Psw16 = (unsigned short*)Psw;

    int tmax = 2 * qb + 1;
    for (int tile = 0; tile <= tmax; ++tile) {
        int s0 = tile * 64;
        __syncthreads();                      // prior tile's LDS reads done (also Q frags)
        {   // stage K tile raw: Ks[s][d] (512 threads, 1 uint4 each)
            int s = tid >> 3, dg = (tid & 7) * 8;
            *(uint4*)(KsS + s * 72 + dg) =
                *(const uint4*)(q16 + (tokbase + s0 + s) * 1536 + koff + dg);
        }
        {   // stage V transposed: Vt[d][s], packed u32 (s even/odd pair)
            int sp = (tid & 31) * 2, dg4 = (tid >> 5) * 4;
            const unsigned short* r0p = q16 + (tokbase + s0 + sp) * 1536 + voff + dg4;
            uint2 va = *(const uint2*)r0p;
            uint2 vb = *(const uint2*)(r0p + 1536);
            unsigned a0[2] = {va.x, va.y};
            unsigned b0[2] = {vb.x, vb.y};
#pragma unroll
            for (int i = 0; i < 2; ++i) {
                unsigned p0 = (a0[i] & 0xffffu) | (b0[i] << 16);
                unsigned p1 = (a0[i] >> 16) | (b0[i] & 0xffff0000u);
                *(unsigned*)(VtS + (dg4 + 2 * i) * 72 + sp)     = p0;
                *(unsigned*)(VtS + (dg4 + 2 * i + 1) * 72 + sp) = p1;
            }
        }
        __syncthreads();
        if (tile == tmax && wave < 4) continue;   // fully masked for waves 0-3
        // ---- QK^T: S[16 q][64 s] per wave (base-2 scaled scores)
        f32x4 Sc[4];
#pragma unroll
        for (int st = 0; st < 4; ++st) Sc[st] = (f32x4){0.f, 0.f, 0.f, 0.f};
#pragma unroll
        for (int ks = 0; ks < 2; ++ks)
#pragma unroll
            for (int st = 0; st < 4; ++st) {
                short8 bk = *(const short8*)(KsS + (st * 16 + c) * 72 + ks * 32 + g * 8);
                Sc[st] = __builtin_amdgcn_mfma_f32_16x16x32_bf16(aq[ks], bk, Sc[st], 0, 0, 0);
            }
        if (tile >= 2 * qb) {                 // diagonal-straddling tiles
            int qg = base + wave * 16 + g * 4;
#pragma unroll
            for (int st = 0; st < 4; ++st) {
                int sg = s0 + st * 16 + c;
#pragma unroll
                for (int r = 0; r < 4; ++r)
                    if (sg > qg + r) Sc[st][r] = -1e30f;
            }
        }
        // ---- online softmax (per q-row = per reg; 16-lane subgroup reductions)
        float pr[4][4], cc[4];
#pragma unroll
        for (int r = 0; r < 4; ++r) {
            float mv = fmaxf(fmaxf(Sc[0][r], Sc[1][r]), fmaxf(Sc[2][r], Sc[3][r]));
#pragma unroll
            for (int off = 1; off < 16; off <<= 1)
                mv = fmaxf(mv, __shfl_xor(mv, off, 64));
            float mn = fmaxf(mrow[r], mv);
            cc[r] = exp2f(mrow[r] - mn);
            mrow[r] = mn;
            float s = 0.f;
#pragma unroll
            for (int st = 0; st < 4; ++st) {
                float p = exp2f(Sc[st][r] - mn);
                pr[st][r] = p;
                s += p;
            }
#pragma unroll
            for (int off = 1; off < 16; off <<= 1)
                s += __shfl_xor(s, off, 64);
            lrow[r] = lrow[r] * cc[r] + s;
        }
        // ---- P -> LDS bf16 [q][s] (same-wave region; DS in-order, no barrier)
#pragma unroll
        for (int st = 0; st < 4; ++st)
#pragma unroll
            for (int r = 0; r < 4; ++r)
                Psw16[(g * 4 + r) * 72 + st * 16 + c] = f2bfu(pr[st][r]);
#pragma unroll
        for (int dt = 0; dt < 4; ++dt)
#pragma unroll
            for (int r = 0; r < 4; ++r)
                acc[dt][r] *= cc[r];
        // ---- PV: O[16 q][64 d] accumulate
#pragma unroll
        for (int ks = 0; ks < 2; ++ks) {
            short8 ap = *(const short8*)(Psw + c * 72 + ks * 32 + g * 8);
#pragma unroll
            for (int dt = 0; dt < 4; ++dt) {
                short8 bv = *(const short8*)(VtS + (dt * 16 + c) * 72 + ks * 32 + g * 8);
                acc[dt] = __builtin_amdgcn_mfma_f32_16x16x32_bf16(ap, bv, acc[dt], 0, 0, 0);
            }
        }
    }
    // ---- epilogue: O[q][d] = acc/l -> o_bf [B*T][512]
    float rl[4];
#pragma unroll
    for (int r = 0; r < 4; ++r) rl[r] = 1.0f / lrow[r];
#pragma unroll
    for (int dt = 0; dt < 4; ++dt)
#pragma unroll
        for (int r = 0; r < 4; ++r) {
            int row = base + wave * 16 + g * 4 + r;
            float o = acc[dt][r] * rl[r];
            ob[(tokbase + row) * 512 + h * 64 + dt * 16 + c] = __float2bfloat16(o);
        }
}

// ---------------------------------------------------------------------------
extern "C" void kernel_launch(void* const* d_in, const int* in_sizes, int n_in,
                              void* d_out, int out_size, void* d_ws, size_t ws_size,
                              hipStream_t stream) {
    const float* x   = (const float*)d_in[0];
    const float* Wq  = (const float*)d_in[1];
    const float* Wk  = (const float*)d_in[2];
    const float* Wv  = (const float*)d_in[3];
    const float* Wo  = (const float*)d_in[4];
    const float* bo  = (const float*)d_in[5];
    const float* W1  = (const float*)d_in[6];
    const float* b1  = (const float*)d_in[7];
    const float* W2  = (const float*)d_in[8];
    const float* b2  = (const float*)d_in[9];
    const float* g1  = (const float*)d_in[10];
    const float* be1 = (const float*)d_in[11];
    const float* g2  = (const float*)d_in[12];
    const float* be2 = (const float*)d_in[13];
    float* out = (float*)d_out;

    // Workspace layout (byte offsets, 16B aligned). Peak use ~98 MB.
    char* ws = (char*)d_ws;
    __hip_bfloat16* bqT    = (__hip_bfloat16*)(ws);                  // [1536][512]
    __hip_bfloat16* woT    = (__hip_bfloat16*)(ws + 1572864);        // [512][512]
    __hip_bfloat16* w1T    = (__hip_bfloat16*)(ws + 2097152);        // [4096][512]
    __hip_bfloat16* w2T    = (__hip_bfloat16*)(ws + 6291456);        // [512][4096]
    float*          xn     = (float*)(ws + 10485760);                // [8192][512] fp32
    __hip_bfloat16* xn_bf  = (__hip_bfloat16*)(ws + 27262976);       // [8192][512] bf16
    __hip_bfloat16* qkv_bf = (__hip_bfloat16*)(ws + 35651584);       // [8192][1536] bf16
    __hip_bfloat16* o_bf   = (__hip_bfloat16*)(ws + 60817408);       // [8192][512] bf16
    __hip_bfloat16* h_bf   = (__hip_bfloat16*)(ws + 35651584);       // [8192][4096] overlay

    // 1. LN1: xn = LN(x)+bo (fp32 residual base), xn_bf = LN(x) (bf16)
    ln_kernel<<<Mrows, 256, 0, stream>>>(x, g1, be1, bo, xn, xn_bf);
    // 2. weight repacks to bf16 [N][K]
    repack_qkv_t<<<192, 256, 0, stream>>>(Wq, Wk, Wv, bqT);
    transpose_bf16<<<dim3(8, 8),  256, 0, stream>>>(Wo, woT, 512, 512);
    transpose_bf16<<<dim3(64, 8), 256, 0, stream>>>(W1, w1T, 512, HIDs);
    transpose_bf16<<<dim3(8, 64), 256, 0, stream>>>(W2, w2T, HIDs, 512);
    // 3. qkv = xn @ Wqkv  -> bf16   (grid 12x64)
    mfma_gemm<<<768, 256, 0, stream>>>(
        xn_bf, 512, bqT, 512, nullptr, qkv_bf, 1536, 512, nullptr, 0, 12, 64);
    // 4. causal attention (MFMA flash, 128-row Q blocks) -> o_bf
    attn_mfma<<<Bsz * Hh * (Tt / 128), 512, 0, stream>>>(qkv_bf, o_bf);
    // 5. xn(=x2) += o @ Wo   (grid 4x64x2, split-K=2, atomic accumulate)
    mfma_gemm<<<512, 256, 0, stream>>>(
        o_bf, 512, woT, 512, xn, nullptr, 512, 256, nullptr, 4, 4, 64);
    // 6. LN2: out = LN(x2)+b2 (fp32, final residual base), xn_bf = LN(x2)
    ln_kernel<<<Mrows, 256, 0, stream>>>(xn, g2, be2, b2, out, xn_bf);
    // 7. h = relu(xn2 @ W1 + b1)  (grid 32x64)
    mfma_gemm<<<2048, 256, 0, stream>>>(
        xn_bf, 512, w1T, 512, nullptr, h_bf, HIDs, 512, b1, 2, 32, 64);
    // 8. out += h @ W2  (grid 4x64x4, split-K=4, atomic accumulate)
    mfma_gemm<<<1024, 256, 0, stream>>>(
        h_bf, HIDs, w2T, HIDs, out, nullptr, 512, 1024, nullptr, 4, 4, 64);
}

// Round 7
// 412.626 us; speedup vs baseline: 15.0716x; 1.0931x over previous
//
#include <hip/hip_runtime.h>
#include <hip/hip_bf16.h>
#include <math.h>

// Problem constants (B,T,E)=(4,2048,512), H=8, D=64, HID=H*E=4096.
#define Bsz 4
#define Tt 2048
#define Ee 512
#define Hh 8
#define Dd 64
#define HIDs 4096
#define Mrows (Bsz * Tt)   // 8192 token rows

typedef __attribute__((ext_vector_type(8))) short short8;   // 8 bf16 (4 VGPRs)
typedef __attribute__((ext_vector_type(4))) float f32x4;    // MFMA accumulator

__device__ __forceinline__ unsigned short f2bfu(float f) {   // RNE float->bf16 bits
    unsigned u = __float_as_uint(f);
    return (unsigned short)((u + 0x7fffu + ((u >> 16) & 1u)) >> 16);
}
__device__ __forceinline__ unsigned scale2(unsigned w, float s) {  // 2xbf16 *= s
    float lo = __uint_as_float(w << 16) * s;
    float hi = __uint_as_float(w & 0xffff0000u) * s;
    return (unsigned)f2bfu(lo) | ((unsigned)f2bfu(hi) << 16);
}

// ---------------------------------------------------------------------------
// LayerNorm: one 256-thread block per row of 512.
// out_f = LN(x)*g+b + addb[col]  (fp32; addb folds the NEXT stage's bias)
// out_bf = LN(x)*g+b             (bf16 GEMM operand, no addb)
__global__ __launch_bounds__(256) void ln_kernel(const float* __restrict__ x,
        const float* __restrict__ g, const float* __restrict__ b,
        const float* __restrict__ addb,
        float* __restrict__ out_f, __hip_bfloat16* __restrict__ out_bf) {
    int row = blockIdx.x;
    int tid = threadIdx.x;
    const float* xr = x + (size_t)row * Ee;
    float v0 = xr[tid];
    float v1 = xr[tid + 256];
    float s = v0 + v1;
    float sq = v0 * v0 + v1 * v1;
#pragma unroll
    for (int off = 32; off > 0; off >>= 1) {
        s  += __shfl_xor(s, off, 64);
        sq += __shfl_xor(sq, off, 64);
    }
    __shared__ float ls[4], lq[4];
    int wid = tid >> 6, lane = tid & 63;
    if (lane == 0) { ls[wid] = s; lq[wid] = sq; }
    __syncthreads();
    s  = ls[0] + ls[1] + ls[2] + ls[3];
    sq = lq[0] + lq[1] + lq[2] + lq[3];
    float mean = s * (1.0f / Ee);
    float var  = sq * (1.0f / Ee) - mean * mean;   // biased var, like jnp.var
    float rstd = rsqrtf(var + 1e-5f);
    float o0 = (v0 - mean) * rstd * g[tid]       + b[tid];
    float o1 = (v1 - mean) * rstd * g[tid + 256] + b[tid + 256];
    float* orow = out_f + (size_t)row * Ee;
    orow[tid]       = o0 + addb[tid];
    orow[tid + 256] = o1 + addb[tid + 256];
    __hip_bfloat16* brow = out_bf + (size_t)row * Ee;
    brow[tid]       = __float2bfloat16(o0);
    brow[tid + 256] = __float2bfloat16(o1);
}

// ---------------------------------------------------------------------------
// Generic fp32 [R][C] -> bf16 [C][R] transpose, 64x64 LDS tiles.
__global__ __launch_bounds__(256) void transpose_bf16(const float* __restrict__ in,
        __hip_bfloat16* __restrict__ outp, int R, int C) {
    __shared__ float tile[64][65];
    int c0 = blockIdx.x * 64, r0 = blockIdx.y * 64;
    int tc = threadIdx.x & 63, tg = threadIdx.x >> 6;
#pragma unroll
    for (int i = 0; i < 16; ++i) {
        int r = tg * 16 + i;
        tile[r][tc] = in[(size_t)(r0 + r) * C + c0 + tc];
    }
    __syncthreads();
#pragma unroll
    for (int i = 0; i < 16; ++i) {
        int cc = tg * 16 + i;
        outp[(size_t)(c0 + cc) * R + r0 + tc] = __float2bfloat16(tile[tc][cc]);
    }
}

// ---------------------------------------------------------------------------
// Repack Wq/Wk/Wv [H,E,D] fp32 -> bqT [3*H*D][E] bf16 (row c=p*512+h*64+d).
__global__ __launch_bounds__(256) void repack_qkv_t(const float* __restrict__ Wq,
        const float* __restrict__ Wk, const float* __restrict__ Wv,
        __hip_bfloat16* __restrict__ bqT) {
    int blk = blockIdx.x;            // p*64 + h*8 + et
    int p = blk >> 6, h = (blk >> 3) & 7, et = blk & 7;
    const float* W = (p == 0) ? Wq : ((p == 1) ? Wk : Wv);
    __shared__ float tile[64][65];
    int td = threadIdx.x & 63, tg = threadIdx.x >> 6;
#pragma unroll
    for (int i = 0; i < 16; ++i) {
        int e = tg * 16 + i;
        tile[e][td] = W[((size_t)h * Ee + et * 64 + e) * Dd + td];
    }
    __syncthreads();
#pragma unroll
    for (int i = 0; i < 16; ++i) {
        int d = tg * 16 + i;
        bqT[((size_t)(p * 512 + h * 64 + d)) * Ee + et * 64 + td] = __float2bfloat16(tile[td][d]);
    }
}

// ---------------------------------------------------------------------------
// bf16 MFMA GEMM: 128x128 tile, BK=64 as two 32-wide k-panels,
// global_load_lds width 16. 1D grid with XCD-aware swizzle. Split-K via
// virtual z. Modes: 0: Cb = bf16(acc); 4: atomicAdd(Cf[ci], acc).
__global__ __launch_bounds__(256) void mfma_gemm(
        const __hip_bfloat16* __restrict__ A, int lda,
        const __hip_bfloat16* __restrict__ B, int ldb,
        float* __restrict__ Cf, __hip_bfloat16* __restrict__ Cb, int ldc, int Kc,
        int mode, int nx, int ny) {
    __shared__ __hip_bfloat16 As[2 * 128 * 32];   // [panel][m][k32]
    __shared__ __hip_bfloat16 Bs[2 * 128 * 32];   // [panel][n][k32]
    int tid = threadIdx.x;
    int lane = tid & 63, wave = tid >> 6;
    int wm = wave >> 1, wn = wave & 1;
    int L = blockIdx.x;
    int slots = (int)gridDim.x >> 3;
    int v = (L & 7) * slots + (L >> 3);
    int bx = v % nx;
    int rem = v / nx;
    int by = rem % ny;
    int bz = rem / ny;
    int row0 = by * 128, col0 = bx * 128;
    int kbase = bz * Kc;
    f32x4 acc[4][4];
#pragma unroll
    for (int i = 0; i < 4; ++i)
#pragma unroll
        for (int j = 0; j < 4; ++j) acc[i][j] = (f32x4){0.f, 0.f, 0.f, 0.f};

    int fr = lane & 15;
    int kq = (lane >> 4) << 3;            // fragment k-offset: 0/8/16/24

    for (int k0 = kbase; k0 < kbase + Kc; k0 += 64) {
        __syncthreads();
#pragma unroll
        for (int j = 0; j < 4; ++j) {
            int c  = j * 256 + tid;
            int cb = j * 256 + wave * 64;         // wave-uniform base chunk
            int p  = c >> 9, cp = c & 511;
            int r  = cp >> 2, kg = (cp & 3) << 3;
            int ko = k0 + p * 32 + kg;
            __builtin_amdgcn_global_load_lds(
                (const __attribute__((address_space(1))) void*)(A + (size_t)(row0 + r) * lda + ko),
                (__attribute__((address_space(3))) void*)(As + cb * 8), 16, 0, 0);
            __builtin_amdgcn_global_load_lds(
                (const __attribute__((address_space(1))) void*)(B + (size_t)(col0 + r) * ldb + ko),
                (__attribute__((address_space(3))) void*)(Bs + cb * 8), 16, 0, 0);
        }
        __syncthreads();
#pragma unroll
        for (int ks = 0; ks < 2; ++ks) {
            short8 afr[4], bfr[4];
#pragma unroll
            for (int i = 0; i < 4; ++i) {
                afr[i] = *(const short8*)(As + ks * 4096 + (wm * 64 + i * 16 + fr) * 32 + kq);
                bfr[i] = *(const short8*)(Bs + ks * 4096 + (wn * 64 + i * 16 + fr) * 32 + kq);
            }
#pragma unroll
            for (int i = 0; i < 4; ++i)
#pragma unroll
                for (int j = 0; j < 4; ++j)
                    acc[i][j] = __builtin_amdgcn_mfma_f32_16x16x32_bf16(afr[i], bfr[j], acc[i][j], 0, 0, 0);
        }
    }
    int rq = (lane >> 4) << 2;
#pragma unroll
    for (int i = 0; i < 4; ++i) {
#pragma unroll
        for (int j = 0; j < 4; ++j) {
#pragma unroll
            for (int gidx = 0; gidx < 4; ++gidx) {
                int r = row0 + wm * 64 + i * 16 + rq + gidx;
                int c = col0 + wn * 64 + j * 16 + fr;
                size_t ci = (size_t)r * ldc + c;
                float val = acc[i][j][gidx];
                if (mode == 0) {
                    Cb[ci] = __float2bfloat16(val);
                } else {
                    atomicAdd(Cf + ci, val);
                }
            }
        }
    }
}

// ---------------------------------------------------------------------------
// bf16 MFMA GEMM, 256x128 tile (FFN1): BK=64 two-panel LDS, 4 waves x 64
// rows x 128 cols each. Epilogue: Cb = bf16(relu(acc + bias[c])).
__global__ __launch_bounds__(256) void mfma_gemm256(
        const __hip_bfloat16* __restrict__ A, int lda,
        const __hip_bfloat16* __restrict__ B, int ldb,
        __hip_bfloat16* __restrict__ Cb, int ldc, int K,
        const float* __restrict__ bias, int nx) {
    __shared__ __hip_bfloat16 As[2 * 256 * 32];   // 32 KB [panel][m][k32]
    __shared__ __hip_bfloat16 Bs[2 * 128 * 32];   // 16 KB [panel][n][k32]
    int tid = threadIdx.x;
    int lane = tid & 63, wave = tid >> 6;
    int L = blockIdx.x;
    int slots = (int)gridDim.x >> 3;
    int v = (L & 7) * slots + (L >> 3);
    int bx = v % nx, by = v / nx;
    int row0 = by * 256, col0 = bx * 128;
    f32x4 acc[4][8];
#pragma unroll
    for (int i = 0; i < 4; ++i)
#pragma unroll
        for (int j = 0; j < 8; ++j) acc[i][j] = (f32x4){0.f, 0.f, 0.f, 0.f};

    int fr = lane & 15;
    int kq = (lane >> 4) << 3;

    for (int k0 = 0; k0 < K; k0 += 64) {
        __syncthreads();
        // A: 2048 chunks (2 panels x 256 r x 4 kg)
#pragma unroll
        for (int j = 0; j < 8; ++j) {
            int c  = j * 256 + tid;
            int cb = j * 256 + wave * 64;
            int p  = c >> 10, cp = c & 1023;
            int r  = cp >> 2, kg = (cp & 3) << 3;
            int ko = k0 + p * 32 + kg;
            __builtin_amdgcn_global_load_lds(
                (const __attribute__((address_space(1))) void*)(A + (size_t)(row0 + r) * lda + ko),
                (__attribute__((address_space(3))) void*)(As + cb * 8), 16, 0, 0);
        }
        // B: 1024 chunks
#pragma unroll
        for (int j = 0; j < 4; ++j) {
            int c  = j * 256 + tid;
            int cb = j * 256 + wave * 64;
            int p  = c >> 9, cp = c & 511;
            int r  = cp >> 2, kg = (cp & 3) << 3;
            int ko = k0 + p * 32 + kg;
            __builtin_amdgcn_global_load_lds(
                (const __attribute__((address_space(1))) void*)(B + (size_t)(col0 + r) * ldb + ko),
                (__attribute__((address_space(3))) void*)(Bs + cb * 8), 16, 0, 0);
        }
        __syncthreads();
#pragma unroll
        for (int ks = 0; ks < 2; ++ks) {
            short8 afr[4], bfr[8];
#pragma unroll
            for (int i = 0; i < 4; ++i)
                afr[i] = *(const short8*)(As + ks * 8192 + (wave * 64 + i * 16 + fr) * 32 + kq);
#pragma unroll
            for (int j = 0; j < 8; ++j)
                bfr[j] = *(const short8*)(Bs + ks * 4096 + (j * 16 + fr) * 32 + kq);
#pragma unroll
            for (int i = 0; i < 4; ++i)
#pragma unroll
                for (int j = 0; j < 8; ++j)
                    acc[i][j] = __builtin_amdgcn_mfma_f32_16x16x32_bf16(afr[i], bfr[j], acc[i][j], 0, 0, 0);
        }
    }
    int rq = (lane >> 4) << 2;
    float bv[8];
#pragma unroll
    for (int j = 0; j < 8; ++j) bv[j] = bias[col0 + j * 16 + fr];
#pragma unroll
    for (int i = 0; i < 4; ++i) {
#pragma unroll
        for (int j = 0; j < 8; ++j) {
#pragma unroll
            for (int gidx = 0; gidx < 4; ++gidx) {
                int r = row0 + wave * 64 + i * 16 + rq + gidx;
                int c = col0 + j * 16 + fr;
                float t = acc[i][j][gidx] + bv[j];
                Cb[(size_t)r * ldc + c] = __float2bfloat16(t > 0.f ? t : 0.f);
            }
        }
    }
}

// ---------------------------------------------------------------------------
// MFMA flash attention, no-max softmax. One block = 128 Q rows of one (b,h);
// 8 waves x 16 rows. Scores are bounded (LN-scale inputs, T^-0.5 scale), so
// exp2 without max subtraction is safe -> no cross-lane reductions at all.
// Row-sum l accumulated on the matrix pipe via a B=ones MFMA.
__global__ __launch_bounds__(512) void attn_mfma(const __hip_bfloat16* __restrict__ qkvb,
        __hip_bfloat16* __restrict__ ob) {
    __shared__ __hip_bfloat16 KsS[64 * 72];     // K tile [s][d], pad 72
    __shared__ __hip_bfloat16 VtS[64 * 72];     // V^T tile [d][s], pad 72
    __shared__ __hip_bfloat16 PsS[8 * 16 * 72]; // P [wave][q][s] bf16; Q overlays
    __hip_bfloat16* Qs = PsS;                   // Q staging [128 q][72]

    const unsigned short* q16 = (const unsigned short*)qkvb;
    int tid  = threadIdx.x;
    int lane = tid & 63, wave = tid >> 6;
    int g = lane >> 4, c = lane & 15;
    int blk = blockIdx.x;
    int qb  = 15 - (blk >> 5);                // global heavy-first
    int bh  = blk & 31;
    int b = bh >> 3, h = bh & 7;
    int base = qb * 128;
    size_t tokbase = (size_t)b * Tt;
    int qoff = h * 64, koff = 512 + h * 64, voff = 1024 + h * 64;
    // T**-0.5 * log2(e): softmax computed with exp2, fixed max=0
    const float qscale = 0.022097086912079608f * 1.4426950408889634f;

    // ---- stage Q (pre-scaled) into Qs[q][72], 128 rows
    {
        int q = tid >> 2, dg = (tid & 3) * 16;
        const unsigned short* src = q16 + (tokbase + base + q) * 1536 + qoff + dg;
        uint4 a  = *(const uint4*)src;
        uint4 b4 = *(const uint4*)(src + 8);
        uint4 ra, rb;
        ra.x = scale2(a.x, qscale);  ra.y = scale2(a.y, qscale);
        ra.z = scale2(a.z, qscale);  ra.w = scale2(a.w, qscale);
        rb.x = scale2(b4.x, qscale); rb.y = scale2(b4.y, qscale);
        rb.z = scale2(b4.z, qscale); rb.w = scale2(b4.w, qscale);
        *(uint4*)(Qs + q * 72 + dg)     = ra;
        *(uint4*)(Qs + q * 72 + dg + 8) = rb;
    }
    __syncthreads();
    // ---- extract this wave's Q fragments once (A: m=lane&15=q, k=quad*8+j)
    short8 aq[2];
    aq[0] = *(const short8*)(Qs + (wave * 16 + c) * 72 + g * 8);
    aq[1] = *(const short8*)(Qs + (wave * 16 + c) * 72 + 32 + g * 8);

    short8 ones;
#pragma unroll
    for (int i = 0; i < 8; ++i) ones[i] = (short)0x3F80;   // bf16 1.0

    f32x4 acc[4];
#pragma unroll
    for (int dt = 0; dt < 4; ++dt) acc[dt] = (f32x4){0.f, 0.f, 0.f, 0.f};
    f32x4 accL = (f32x4){0.f, 0.f, 0.f, 0.f};   // row-sums of P
    __hip_bfloat16* Psw = PsS + wave * (16 * 72);
    unsigned short* Psw16 = (unsigned short*)Psw;

    int tmax = 2 * qb + 1;
    for (int tile = 0; tile <= tmax; ++tile) {
        int s0 = tile * 64;
        __syncthreads();                      // prior tile's LDS reads done (also Q frags)
        {   // stage K tile raw: Ks[s][d] (512 threads, 1 uint4 each)
            int s = tid >> 3, dg = (tid & 7) * 8;
            *(uint4*)(KsS + s * 72 + dg) =
                *(const uint4*)(q16 + (tokbase + s0 + s) * 1536 + koff + dg);
        }
        {   // stage V transposed: Vt[d][s], packed u32 (s even/odd pair)
            int sp = (tid & 31) * 2, dg4 = (tid >> 5) * 4;
            const unsigned short* r0p = q16 + (tokbase + s0 + sp) * 1536 + voff + dg4;
            uint2 va = *(const uint2*)r0p;
            uint2 vb = *(const uint2*)(r0p + 1536);
            unsigned a0[2] = {va.x, va.y};
            unsigned b0[2] = {vb.x, vb.y};
#pragma unroll
            for (int i = 0; i < 2; ++i) {
                unsigned p0 = (a0[i] & 0xffffu) | (b0[i] << 16);
                unsigned p1 = (a0[i] >> 16) | (b0[i] & 0xffff0000u);
                *(unsigned*)(VtS + (dg4 + 2 * i) * 72 + sp)     = p0;
                *(unsigned*)(VtS + (dg4 + 2 * i + 1) * 72 + sp) = p1;
            }
        }
        __syncthreads();
        if (tile == tmax && wave < 4) continue;   // fully masked for waves 0-3
        // ---- QK^T: S[16 q][64 s] per wave (base-2 scaled scores)
        f32x4 Sc[4];
#pragma unroll
        for (int st = 0; st < 4; ++st) Sc[st] = (f32x4){0.f, 0.f, 0.f, 0.f};
#pragma unroll
        for (int ks = 0; ks < 2; ++ks)
#pragma unroll
            for (int st = 0; st < 4; ++st) {
                short8 bk = *(const short8*)(KsS + (st * 16 + c) * 72 + ks * 32 + g * 8);
                Sc[st] = __builtin_amdgcn_mfma_f32_16x16x32_bf16(aq[ks], bk, Sc[st], 0, 0, 0);
            }
        if (tile >= 2 * qb) {                 // diagonal-straddling tiles
            int qg = base + wave * 16 + g * 4;
#pragma unroll
            for (int st = 0; st < 4; ++st) {
                int sg = s0 + st * 16 + c;
#pragma unroll
                for (int r = 0; r < 4; ++r)
                    if (sg > qg + r) Sc[st][r] = -1e30f;
            }
        }
        // ---- p = exp2(score); straight to LDS (same-wave region, no barrier)
#pragma unroll
        for (int st = 0; st < 4; ++st)
#pragma unroll
            for (int r = 0; r < 4; ++r)
                Psw16[(g * 4 + r) * 72 + st * 16 + c] =
                    f2bfu(__builtin_amdgcn_exp2f(Sc[st][r]));
        // ---- PV: O[16 q][64 d] accumulate; l via ones-MFMA
#pragma unroll
        for (int ks = 0; ks < 2; ++ks) {
            short8 ap = *(const short8*)(Psw + c * 72 + ks * 32 + g * 8);
            accL = __builtin_amdgcn_mfma_f32_16x16x32_bf16(ap, ones, accL, 0, 0, 0);
#pragma unroll
            for (int dt = 0; dt < 4; ++dt) {
                short8 bv = *(const short8*)(VtS + (dt * 16 + c) * 72 + ks * 32 + g * 8);
                acc[dt] = __builtin_amdgcn_mfma_f32_16x16x32_bf16(ap, bv, acc[dt], 0, 0, 0);
            }
        }
    }
    // ---- epilogue: O[q][d] = acc/l -> o_bf [B*T][512]
    float rl[4];
#pragma unroll
    for (int r = 0; r < 4; ++r) rl[r] = 1.0f / accL[r];
#pragma unroll
    for (int dt = 0; dt < 4; ++dt)
#pragma unroll
        for (int r = 0; r < 4; ++r) {
            int row = base + wave * 16 + g * 4 + r;
            float o = acc[dt][r] * rl[r];
            ob[(tokbase + row) * 512 + h * 64 + dt * 16 + c] = __float2bfloat16(o);
        }
}

// ---------------------------------------------------------------------------
extern "C" void kernel_launch(void* const* d_in, const int* in_sizes, int n_in,
                              void* d_out, int out_size, void* d_ws, size_t ws_size,
                              hipStream_t stream) {
    const float* x   = (const float*)d_in[0];
    const float* Wq  = (const float*)d_in[1];
    const float* Wk  = (const float*)d_in[2];
    const float* Wv  = (const float*)d_in[3];
    const float* Wo  = (const float*)d_in[4];
    const float* bo  = (const float*)d_in[5];
    const float* W1  = (const float*)d_in[6];
    const float* b1  = (const float*)d_in[7];
    const float* W2  = (const float*)d_in[8];
    const float* b2  = (const float*)d_in[9];
    const float* g1  = (const float*)d_in[10];
    const float* be1 = (const float*)d_in[11];
    const float* g2  = (const float*)d_in[12];
    const float* be2 = (const float*)d_in[13];
    float* out = (float*)d_out;

    // Workspace layout (byte offsets, 16B aligned). Peak use ~98 MB.
    char* ws = (char*)d_ws;
    __hip_bfloat16* bqT    = (__hip_bfloat16*)(ws);                  // [1536][512]
    __hip_bfloat16* woT    = (__hip_bfloat16*)(ws + 1572864);        // [512][512]
    __hip_bfloat16* w1T    = (__hip_bfloat16*)(ws + 2097152);        // [4096][512]
    __hip_bfloat16* w2T    = (__hip_bfloat16*)(ws + 6291456);        // [512][4096]
    float*          xn     = (float*)(ws + 10485760);                // [8192][512] fp32
    __hip_bfloat16* xn_bf  = (__hip_bfloat16*)(ws + 27262976);       // [8192][512] bf16
    __hip_bfloat16* qkv_bf = (__hip_bfloat16*)(ws + 35651584);       // [8192][1536] bf16
    __hip_bfloat16* o_bf   = (__hip_bfloat16*)(ws + 60817408);       // [8192][512] bf16
    __hip_bfloat16* h_bf   = (__hip_bfloat16*)(ws + 35651584);       // [8192][4096] overlay

    // 1. LN1: xn = LN(x)+bo (fp32 residual base), xn_bf = LN(x) (bf16)
    ln_kernel<<<Mrows, 256, 0, stream>>>(x, g1, be1, bo, xn, xn_bf);
    // 2. weight repacks to bf16 [N][K]
    repack_qkv_t<<<192, 256, 0, stream>>>(Wq, Wk, Wv, bqT);
    transpose_bf16<<<dim3(8, 8),  256, 0, stream>>>(Wo, woT, 512, 512);
    transpose_bf16<<<dim3(64, 8), 256, 0, stream>>>(W1, w1T, 512, HIDs);
    transpose_bf16<<<dim3(8, 64), 256, 0, stream>>>(W2, w2T, HIDs, 512);
    // 3. qkv = xn @ Wqkv  -> bf16   (grid 12x64)
    mfma_gemm<<<768, 256, 0, stream>>>(
        xn_bf, 512, bqT, 512, nullptr, qkv_bf, 1536, 512, 0, 12, 64);
    // 4. causal attention (MFMA flash, 128-row Q blocks) -> o_bf
    attn_mfma<<<Bsz * Hh * (Tt / 128), 512, 0, stream>>>(qkv_bf, o_bf);
    // 5. xn(=x2) += o @ Wo   (grid 4x64x2, split-K=2, atomic accumulate)
    mfma_gemm<<<512, 256, 0, stream>>>(
        o_bf, 512, woT, 512, xn, nullptr, 512, 256, 4, 4, 64);
    // 6. LN2: out = LN(x2)+b2 (fp32, final residual base), xn_bf = LN(x2)
    ln_kernel<<<Mrows, 256, 0, stream>>>(xn, g2, be2, b2, out, xn_bf);
    // 7. h = relu(xn2 @ W1 + b1)  (256x128 tiles, grid 32x32)
    mfma_gemm256<<<1024, 256, 0, stream>>>(
        xn_bf, 512, w1T, 512, h_bf, HIDs, 512, b1, 32);
    // 8. out += h @ W2  (grid 4x64x4, split-K=4, atomic accumulate)
    mfma_gemm<<<1024, 256, 0, stream>>>(
        h_bf, HIDs, w2T, HIDs, out, nullptr, 512, 1024, 4, 4, 64);
}